// Round 5
// baseline (3277.571 us; speedup 1.0000x reference)
//
#include <hip/hip_runtime.h>
#include <hip/hip_bf16.h>
#include <stdint.h>

typedef __bf16 bf16;
typedef __bf16 bf16x8 __attribute__((ext_vector_type(8)));
typedef float  f32x4v __attribute__((ext_vector_type(4)));

// ---------------------------------------------------------------- reductions
__device__ __forceinline__ float block_reduce_sum256(float v) {
    __shared__ float red[256];
    int tid = threadIdx.x;
    red[tid] = v; __syncthreads();
    #pragma unroll
    for (int s = 128; s > 0; s >>= 1) {
        if (tid < s) red[tid] += red[tid + s];
        __syncthreads();
    }
    float r = red[0]; __syncthreads();
    return r;
}

__device__ __forceinline__ float block_reduce_max256(float v) {
    __shared__ float redm[256];
    int tid = threadIdx.x;
    redm[tid] = v; __syncthreads();
    #pragma unroll
    for (int s = 128; s > 0; s >>= 1) {
        if (tid < s) redm[tid] = fmaxf(redm[tid], redm[tid + s]);
        __syncthreads();
    }
    float r = redm[0]; __syncthreads();
    return r;
}

// ---------------------------------------------------------------- f32 GEMM (VALU)
// C[M x N] = act(alpha * A @ Bt^T + bias); A [M][K], Bt [N][K] both f32 row-major.
// BM=64, BN in {64,128}; 256 threads; micro-tile 4 x (BN/16).
// Optional z-batch via element strides (sAz/sBz/sCz).
template<int BN, bool RELU, bool TRANS>
__global__ __launch_bounds__(256)
void gemm_f32(const float* __restrict__ A, const float* __restrict__ Bt,
              const float* __restrict__ bias, float* __restrict__ C,
              int K, int lda, int ldb, int ldc, float alpha,
              long sAz, long sBz, long sCz)
{
    constexpr int BM = 64, TK = 16, PAD = 4;
    constexpr int RN = BN / 16;
    __shared__ float As[TK][BM + PAD];
    __shared__ float Bs[TK][BN + PAD];

    const int tid = threadIdx.x;
    const long bm = (long)blockIdx.y * BM;
    const long bn = (long)blockIdx.x * BN;
    A  += (long)blockIdx.z * sAz;
    Bt += (long)blockIdx.z * sBz;
    C  += (long)blockIdx.z * sCz;

    const int arow = tid >> 2, ac = tid & 3;       // A staging: 64 rows x 4 float4
    const int tm = (tid >> 4) * 4;                 // 0..60
    const int tn = (tid & 15) * 4;                 // 0..60

    float acc[4][RN];
    #pragma unroll
    for (int i = 0; i < 4; i++)
        #pragma unroll
        for (int j = 0; j < RN; j++) acc[i][j] = 0.f;

    for (int k0 = 0; k0 < K; k0 += TK) {
        float4 av = *(const float4*)&A[(bm + arow) * (long)lda + k0 + ac * 4];
        As[ac*4+0][arow] = av.x; As[ac*4+1][arow] = av.y;
        As[ac*4+2][arow] = av.z; As[ac*4+3][arow] = av.w;
        if (BN == 64) {
            float4 bv = *(const float4*)&Bt[(bn + arow) * (long)ldb + k0 + ac * 4];
            Bs[ac*4+0][arow] = bv.x; Bs[ac*4+1][arow] = bv.y;
            Bs[ac*4+2][arow] = bv.z; Bs[ac*4+3][arow] = bv.w;
        } else {
            const int brow = tid >> 1, bc = tid & 1;  // 128 rows x 2 float4 (8 k each)
            #pragma unroll
            for (int h = 0; h < 2; h++) {
                float4 bv = *(const float4*)&Bt[(bn + brow) * (long)ldb + k0 + bc * 8 + h * 4];
                const int kk = bc * 8 + h * 4;
                Bs[kk+0][brow] = bv.x; Bs[kk+1][brow] = bv.y;
                Bs[kk+2][brow] = bv.z; Bs[kk+3][brow] = bv.w;
            }
        }
        __syncthreads();
        #pragma unroll
        for (int kk = 0; kk < TK; kk++) {
            float4 a4 = *(const float4*)&As[kk][tm];
            float ar[4] = {a4.x, a4.y, a4.z, a4.w};
            #pragma unroll
            for (int g = 0; g < RN / 4; g++) {
                float4 b4 = *(const float4*)&Bs[kk][tn + g * 64];
                float br[4] = {b4.x, b4.y, b4.z, b4.w};
                #pragma unroll
                for (int i = 0; i < 4; i++)
                    #pragma unroll
                    for (int j = 0; j < 4; j++)
                        acc[i][g*4+j] = fmaf(ar[i], br[j], acc[i][g*4+j]);
            }
        }
        __syncthreads();
    }

    #pragma unroll
    for (int g = 0; g < RN / 4; g++) {
        #pragma unroll
        for (int j = 0; j < 4; j++) {
            const long col = bn + tn + g * 64 + j;
            const float bv = bias ? bias[col] : 0.f;
            #pragma unroll
            for (int i = 0; i < 4; i++) {
                float v = acc[i][g*4+j] * alpha + bv;
                if (RELU) v = fmaxf(v, 0.f);
                if (TRANS) C[col * (long)ldc + (bm + tm + i)] = v;
                else       C[(bm + tm + i) * (long)ldc + col] = v;
            }
        }
    }
}

// ---------------------------------------------------------------- PV split-K (f32, atomicAdd epilogue)
// grid: x = 128/64, y = CH/64, z = h*8 + s. ctx must be pre-zeroed.
__global__ __launch_bounds__(256)
void pv_f32_splitk(const float* __restrict__ P, const float* __restrict__ Vt,
                   float* __restrict__ Cx, int lda, int ldb, int ldc,
                   long hA, long hB, long hC, int KS)
{
    constexpr int BM = 64, TK = 16, PAD = 4;
    __shared__ float As[TK][BM + PAD];
    __shared__ float Bs[TK][BM + PAD];

    const int tid = threadIdx.x;
    const int z = blockIdx.z, h = z >> 3, s = z & 7;
    const float* A  = P  + (long)h * hA;
    const float* Bt = Vt + (long)h * hB;
    float* C        = Cx + (long)h * hC;
    const long bm = (long)blockIdx.y * BM;
    const long bn = (long)blockIdx.x * BM;

    const int arow = tid >> 2, ac = tid & 3;
    const int tm = (tid >> 4) * 4, tn = (tid & 15) * 4;

    float acc[4][4];
    #pragma unroll
    for (int i = 0; i < 4; i++)
        #pragma unroll
        for (int j = 0; j < 4; j++) acc[i][j] = 0.f;

    const int kbeg = s * KS, kend = kbeg + KS;
    for (int k0 = kbeg; k0 < kend; k0 += TK) {
        float4 av = *(const float4*)&A[(bm + arow) * (long)lda + k0 + ac * 4];
        As[ac*4+0][arow] = av.x; As[ac*4+1][arow] = av.y;
        As[ac*4+2][arow] = av.z; As[ac*4+3][arow] = av.w;
        float4 bv = *(const float4*)&Bt[(bn + arow) * (long)ldb + k0 + ac * 4];
        Bs[ac*4+0][arow] = bv.x; Bs[ac*4+1][arow] = bv.y;
        Bs[ac*4+2][arow] = bv.z; Bs[ac*4+3][arow] = bv.w;
        __syncthreads();
        #pragma unroll
        for (int kk = 0; kk < TK; kk++) {
            float4 a4 = *(const float4*)&As[kk][tm];
            float4 b4 = *(const float4*)&Bs[kk][tn];
            float ar[4] = {a4.x, a4.y, a4.z, a4.w};
            float br[4] = {b4.x, b4.y, b4.z, b4.w};
            #pragma unroll
            for (int i = 0; i < 4; i++)
                #pragma unroll
                for (int j = 0; j < 4; j++)
                    acc[i][j] = fmaf(ar[i], br[j], acc[i][j]);
        }
        __syncthreads();
    }
    #pragma unroll
    for (int i = 0; i < 4; i++)
        #pragma unroll
        for (int j = 0; j < 4; j++)
            atomicAdd(&C[(bm + tm + i) * (long)ldc + bn + tn + j], acc[i][j]);
}

// ---------------------------------------------------------------- fc2: A bf16 [M][512], B f32 [512][4096] natural, relu, f32 out
__global__ __launch_bounds__(256)
void gemm_fc2(const bf16* __restrict__ A, const float* __restrict__ B,
              const float* __restrict__ bias, float* __restrict__ C,
              int lda, int ldb, int ldc)
{
    constexpr int TK = 32, BM = 128, BN = 128;
    constexpr int WM = 64, WN = 64, RM = 4, RN = 4;
    __shared__ __align__(16) bf16 As[BM * TK];
    __shared__ __align__(16) bf16 Bs2[TK * BN];   // k-major [32][128]

    const int tid  = threadIdx.x;
    const int wave = tid >> 6, lane = tid & 63;
    const int wr = wave >> 1, wc = wave & 1;
    const long bm = (long)blockIdx.y * BM;
    const long bn = (long)blockIdx.x * BN;

    const int srow = lane >> 2;
    const int scol = (lane & 3) << 3;

    const bf16* Ap = A + (bm + wave * 32 + srow) * (long)lda + scol;
    bf16* AsW = &As[(wave * 32 + srow) * TK + scol];

    const int fr = lane & 15, fq = lane >> 4;

    f32x4v acc[RM][RN] = {};

    for (int k0 = 0; k0 < 512; k0 += TK) {
        #pragma unroll
        for (int it = 0; it < 2; it++)
            *(bf16x8*)(AsW + it * 16 * TK) = *(const bf16x8*)(Ap + (long)it * 16 * lda);
        Ap += TK;
        #pragma unroll
        for (int it = 0; it < 2; it++) {
            const int c = tid + it * 256;      // 0..511
            const int k = c >> 4, n8 = c & 15;
            const float* src = B + (long)(k0 + k) * ldb + bn + n8 * 8;
            float4 f0 = *(const float4*)(src);
            float4 f1 = *(const float4*)(src + 4);
            bf16x8 pk;
            pk[0] = (bf16)f0.x; pk[1] = (bf16)f0.y; pk[2] = (bf16)f0.z; pk[3] = (bf16)f0.w;
            pk[4] = (bf16)f1.x; pk[5] = (bf16)f1.y; pk[6] = (bf16)f1.z; pk[7] = (bf16)f1.w;
            *(bf16x8*)&Bs2[k * BN + n8 * 8] = pk;
        }
        __syncthreads();

        bf16x8 af[RM], bfr[RN];
        #pragma unroll
        for (int i = 0; i < RM; i++)
            af[i] = *(const bf16x8*)&As[(wr * WM + i * 16 + fr) * TK + fq * 8];
        #pragma unroll
        for (int j = 0; j < RN; j++) {
            const int col = wc * WN + j * 16 + fr;
            #pragma unroll
            for (int jj = 0; jj < 8; jj++)
                bfr[j][jj] = Bs2[(fq * 8 + jj) * BN + col];
        }
        #pragma unroll
        for (int i = 0; i < RM; i++)
            #pragma unroll
            for (int j = 0; j < RN; j++)
                acc[i][j] = __builtin_amdgcn_mfma_f32_16x16x32_bf16(af[i], bfr[j], acc[i][j], 0, 0, 0);
        __syncthreads();
    }

    #pragma unroll
    for (int i = 0; i < RM; i++) {
        #pragma unroll
        for (int j = 0; j < RN; j++) {
            const long col = bn + wc * WN + j * 16 + fr;
            const float bv = bias[col];
            #pragma unroll
            for (int r = 0; r < 4; r++) {
                const long row = bm + wr * WM + i * 16 + fq * 4 + r;
                C[row * (long)ldc + col] = fmaxf(acc[i][j][r] + bv, 0.f);
            }
        }
    }
}

// ---------------------------------------------------------------- transpose f32 [R][C] -> f32 [C][R]
__global__ void transpose_f32(const float* __restrict__ src, float* __restrict__ dst,
                              int R, int C)
{
    __shared__ float t[32][33];
    const int bx = blockIdx.x * 32;  // over C
    const int by = blockIdx.y * 32;  // over R
    const int x = threadIdx.x, y = threadIdx.y;  // 32 x 8
    #pragma unroll
    for (int i = 0; i < 32; i += 8)
        t[y + i][x] = src[(long)(by + y + i) * C + bx + x];
    __syncthreads();
    #pragma unroll
    for (int i = 0; i < 32; i += 8)
        dst[(long)(bx + y + i) * R + by + x] = t[x][y + i];
}

// ---------------------------------------------------------------- softmax rows in-place (f32), ncols = 4096
__global__ void softmax_rows_f32(float* __restrict__ S)
{
    const long row = blockIdx.x;
    const int tid = threadIdx.x;
    float* s = S + row * 4096L;
    float ev[16];
    float m = -1e30f;
    #pragma unroll
    for (int i = 0; i < 16; i++) { ev[i] = s[tid + (i << 8)]; m = fmaxf(m, ev[i]); }
    m = block_reduce_max256(m);
    float sum = 0.f;
    #pragma unroll
    for (int i = 0; i < 16; i++) { ev[i] = __expf(ev[i] - m); sum += ev[i]; }
    sum = block_reduce_sum256(sum);
    const float inv = 1.f / sum;
    #pragma unroll
    for (int i = 0; i < 16; i++) s[tid + (i << 8)] = ev[i] * inv;
}

// ---------------------------------------------------------------- residual + layernorm (f32, D=512)
__global__ void add_ln_f32(const float* __restrict__ a, const float* __restrict__ b,
                           const float* __restrict__ g, const float* __restrict__ be,
                           float* __restrict__ out)
{
    const long row = blockIdx.x;
    const int tid = threadIdx.x;
    const long base = row * 512L;
    float x0 = a[base + tid]       + b[base + tid];
    float x1 = a[base + tid + 256] + b[base + tid + 256];
    float s = block_reduce_sum256(x0 + x1);
    float mu = s * (1.f / 512.f);
    float d0 = x0 - mu, d1 = x1 - mu;
    float var = block_reduce_sum256(d0 * d0 + d1 * d1) * (1.f / 512.f);
    float invs = rsqrtf(var + 1e-6f);
    out[base + tid]       = d0 * invs * g[tid]       + be[tid];
    out[base + tid + 256] = d1 * invs * g[tid + 256] + be[tid + 256];
}

// ---------------------------------------------------------------- normalize emb rows (f32, E=512)
__global__ void normalize_emb(const float* __restrict__ emb, float* __restrict__ embn)
{
    const long row = blockIdx.x;
    const int tid = threadIdx.x;
    const long base = row * 512L;
    float a0 = emb[base + tid];
    float a1 = emb[base + tid + 256];
    float ss = block_reduce_sum256(a0 * a0 + a1 * a1);
    float sc = rsqrtf(fmaxf(ss, 1e-12f));
    embn[base + tid]       = a0 * sc;
    embn[base + tid + 256] = a1 * sc;
}

// ---------------------------------------------------------------- VQ: argmax over sims row, convert row to one-hot IN PLACE, gather vq_feat
__global__ void vq_select_onehot(float* __restrict__ sims, const float* __restrict__ emb,
                                 float* __restrict__ vq_out)
{
    __shared__ float sv[256];
    __shared__ int   si[256];
    const long row = blockIdx.x;
    const int tid = threadIdx.x;
    float* s = sims + row * 1024L;
    float v0 = s[tid], v1 = s[tid + 256], v2 = s[tid + 512], v3 = s[tid + 768];
    float best = v0; int bi = tid;
    if (v1 > best) { best = v1; bi = tid + 256; }
    if (v2 > best) { best = v2; bi = tid + 512; }
    if (v3 > best) { best = v3; bi = tid + 768; }
    sv[tid] = best; si[tid] = bi; __syncthreads();
    #pragma unroll
    for (int st = 128; st > 0; st >>= 1) {
        if (tid < st) {
            if (sv[tid + st] > sv[tid] ||
                (sv[tid + st] == sv[tid] && si[tid + st] < si[tid])) {
                sv[tid] = sv[tid + st]; si[tid] = si[tid + st];
            }
        }
        __syncthreads();
    }
    const int idx = si[0];
    // one-hot in place (all reads of s happened before the barrier above)
    s[tid]       = (tid       == idx) ? 1.f : 0.f;
    s[tid + 256] = (tid + 256 == idx) ? 1.f : 0.f;
    s[tid + 512] = (tid + 512 == idx) ? 1.f : 0.f;
    s[tid + 768] = (tid + 768 == idx) ? 1.f : 0.f;
    // gather vq_feat row
    const float* er = emb + (long)idx * 512;
    float* vr = vq_out + row * 512L;
    vr[tid]       = er[tid];
    vr[tid + 256] = er[tid + 256];
}

// ---------------------------------------------------------------- f32 -> bf16 convert
__global__ void cvt_f32_bf16(const float* __restrict__ src, bf16* __restrict__ dst, long n4)
{
    const long i = (long)blockIdx.x * blockDim.x + threadIdx.x;
    if (i >= n4) return;
    float4 v = *(const float4*)(src + i * 4);
    bf16 o[4] = { (bf16)v.x, (bf16)v.y, (bf16)v.z, (bf16)v.w };
    *(uint64_t*)(dst + i * 4) = *(uint64_t*)o;
}

// ---------------------------------------------------------------- host side
struct EncW {
    const float *wqT, *wkT, *wvT, *woT, *w1T, *w2T;
    const float *bq, *bk, *bv, *bo, *b1, *b2;
    const float *g1, *be1, *g2, *be2;
};

static void run_encoder_f32(hipStream_t stream, const float* x, const EncW& w,
                            float* qb, float* kb, float* vt, float* ctx,
                            float* S_all, float* out)
{
    const int N = 4096, D = 512, DH = 128, CH = 256;
    const float isq = 0.08838834764831843f;  // 1/sqrt(128)
    // q, k
    gemm_f32<128, false, false><<<dim3(4, 64, 1), 256, 0, stream>>>(
        x, w.wqT, w.bq, qb, D, D, D, D, 1.f, 0, 0, 0);
    gemm_f32<128, false, false><<<dim3(4, 64, 1), 256, 0, stream>>>(
        x, w.wkT, w.bk, kb, D, D, D, D, 1.f, 0, 0, 0);
    // v stored transposed: vt[d][n]
    gemm_f32<128, false, true><<<dim3(4, 64, 1), 256, 0, stream>>>(
        x, w.wvT, w.bv, vt, D, D, D, N, 1.f, 0, 0, 0);
    hipMemsetAsync(ctx, 0, (size_t)N * D * sizeof(float), stream);
    for (int c = 0; c < N / CH; c++) {
        // S_all[h][CH][N] = (Q_h[chunk] K_h^T)/sqrt(dh)
        gemm_f32<128, false, false><<<dim3(N / 128, CH / 64, 4), 256, 0, stream>>>(
            qb + (size_t)c * CH * D, kb, nullptr, S_all,
            DH, D, D, N, isq, 128, 128, (long)CH * N);
        softmax_rows_f32<<<4 * CH, 256, 0, stream>>>(S_all);
        // ctx[chunk][h*128+d] += P_h @ V_h  (split-K=8, atomic)
        pv_f32_splitk<<<dim3(2, CH / 64, 32), 256, 0, stream>>>(
            S_all, vt, ctx + (size_t)c * CH * D, N, N, D,
            (long)CH * N, (long)DH * N, DH, N / 8);
    }
    // attn out projection -> qb; LN1 -> vt (x1); FFN; LN2 -> out
    gemm_f32<128, false, false><<<dim3(4, 64, 1), 256, 0, stream>>>(
        ctx, w.woT, w.bo, qb, D, D, D, D, 1.f, 0, 0, 0);
    add_ln_f32<<<N, 256, 0, stream>>>(x, qb, w.g1, w.be1, vt);
    gemm_f32<128, true, false><<<dim3(4, 64, 1), 256, 0, stream>>>(
        vt, w.w1T, w.b1, kb, D, D, D, D, 1.f, 0, 0, 0);
    gemm_f32<128, false, false><<<dim3(4, 64, 1), 256, 0, stream>>>(
        kb, w.w2T, w.b2, qb, D, D, D, D, 1.f, 0, 0, 0);
    add_ln_f32<<<N, 256, 0, stream>>>(vt, qb, w.g2, w.be2, out);
}

extern "C" void kernel_launch(void* const* d_in, const int* in_sizes, int n_in,
                              void* d_out, int out_size, void* d_ws, size_t ws_size,
                              hipStream_t stream)
{
    const int N = 4096, D = 512, E = 512, F = 4096, KCB = 1024;
    (void)in_sizes; (void)n_in; (void)out_size; (void)d_ws; (void)ws_size;

    const float* x_in  = (const float*)d_in[0];
    const float* fc1_w = (const float*)d_in[33];
    const float* fc1_b = (const float*)d_in[34];
    const float* fc2_w = (const float*)d_in[35];
    const float* fc2_b = (const float*)d_in[36];
    const float* emb   = (const float*)d_in[37];

    // ---- output regions (f32) — context_ind is the ONE-HOT [N, K] matrix!
    float* out0 = (float*)d_out;                  // encoded [N,E]       8 MB
    float* out1 = out0 + (size_t)N * E;           // vq_feat [N,E]       8 MB
    float* out2 = out1 + (size_t)N * E;           // one_hot [N,K]      16 MB
    float* out3 = out2 + (size_t)N * KCB;         // decoded [N,F]      64 MB
    float* out4 = out3 + (size_t)N * F;           // emb copy [K,E]      2 MB

    // ---- arena inside out3 (64 MB), MB offsets; all dead before fc2 writes
    char* arena = (char*)out3;
    const size_t MB = 1024 * 1024;
    float* wTf    = (float*)(arena + 0 * MB);     // [0,6): 6 transposed 512x512 f32 weights
    float* fc1T   = (float*)(arena + 6 * MB);     // [6,7)
    float* qb     = (float*)(arena + 7 * MB);     // [7,15)
    float* kb     = (float*)(arena + 15 * MB);    // [15,23)
    float* vt     = (float*)(arena + 23 * MB);    // [23,31)
    float* ctx    = (float*)(arena + 31 * MB);    // [31,39)
    float* S_all  = (float*)(arena + 39 * MB);    // [39,55): 4 x 256 x 4096 f32
    float* decout = (float*)(arena + 48 * MB);    // [48,56): only written after S_all dead
    bf16*  decb   = (bf16*)(arena + 60 * MB);     // [60,64): bf16 decoder output
    float* sims   = out2;                         // sims [N,K] computed in the one-hot region
    float* embn   = out1;                         // 2 MB of vq_feat region (dead until vq_select)
    bf16*  stage  = (bf16*)out4;                  // 0.5 MB panel staging (emb copied last)

    auto transpose6 = [&](int base_idx) {
        for (int i = 0; i < 6; i++)
            transpose_f32<<<dim3(16, 16), dim3(32, 8), 0, stream>>>(
                (const float*)d_in[base_idx + i], wTf + (size_t)i * 512 * 512, 512, 512);
    };

    EncW ew = { wTf, wTf + 262144, wTf + 2*262144, wTf + 3*262144, wTf + 4*262144, wTf + 5*262144,
                (const float*)d_in[7],  (const float*)d_in[8],  (const float*)d_in[9],
                (const float*)d_in[10], (const float*)d_in[11], (const float*)d_in[12],
                (const float*)d_in[13], (const float*)d_in[14], (const float*)d_in[15],
                (const float*)d_in[16] };
    EncW dw = ew;
    dw.bq = (const float*)d_in[23]; dw.bk = (const float*)d_in[24]; dw.bv = (const float*)d_in[25];
    dw.bo = (const float*)d_in[26]; dw.b1 = (const float*)d_in[27]; dw.b2 = (const float*)d_in[28];
    dw.g1 = (const float*)d_in[29]; dw.be1 = (const float*)d_in[30];
    dw.g2 = (const float*)d_in[31]; dw.be2 = (const float*)d_in[32];

    // ---- phase E: encoder (f32), output -> ctx
    transpose6(1);
    transpose_f32<<<dim3(16, 16), dim3(32, 8), 0, stream>>>(fc1_w, fc1T, 512, 512);
    normalize_emb<<<KCB, 256, 0, stream>>>(emb, embn);
    run_encoder_f32(stream, x_in, ew, qb, kb, vt, ctx, S_all, ctx);

    // ---- phase F: fc1 -> encoded (out0)
    gemm_f32<128, false, false><<<dim3(4, 64, 1), 256, 0, stream>>>(
        ctx, fc1T, fc1_b, out0, D, D, D, E, 1.f, 0, 0, 0);

    // ---- phase V: sims = encoded @ embn^T (f32) into out2; argmax -> one-hot in place + gather
    gemm_f32<128, false, false><<<dim3(8, 64, 1), 256, 0, stream>>>(
        out0, embn, nullptr, sims, E, E, E, KCB, 1.f, 0, 0, 0);
    vq_select_onehot<<<N, 256, 0, stream>>>(sims, emb, out1);

    // ---- phase D: decoder (f32), input = out1 (vq_feat), output -> decout [48,56)
    transpose6(17);
    run_encoder_f32(stream, out1, dw, qb, kb, vt, ctx, S_all, decout);

    // ---- phase G: fc2 + relu (bf16 MFMA). Convert decout -> decb, then two launches:
    // rows [0,3584) read decb in place; rows [3584,4096) read staged copy (decb
    // lives at [60,64) which the second launch's writes cover).
    cvt_f32_bf16<<<(N * D / 4 + 255) / 256, 256, 0, stream>>>(decout, decb, (long)N * D / 4);
    hipMemcpyAsync(stage, decb + (size_t)3584 * D, (size_t)512 * D * sizeof(bf16),
                   hipMemcpyDeviceToDevice, stream);
    gemm_fc2<<<dim3(F / 128, 3584 / 128), 256, 0, stream>>>(
        decb, fc2_w, fc2_b, out3, D, F, F);
    gemm_fc2<<<dim3(F / 128, 512 / 128), 256, 0, stream>>>(
        stage, fc2_w, fc2_b, out3 + (size_t)3584 * F, D, F, F);

    // ---- emb copy last (out4 was panel staging)
    hipMemcpyAsync(out4, emb, (size_t)KCB * E * sizeof(float), hipMemcpyDeviceToDevice, stream);
}

// Round 6
// 1858.325 us; speedup vs baseline: 1.7637x; 1.7637x over previous
//
#include <hip/hip_runtime.h>
#include <hip/hip_bf16.h>
#include <stdint.h>

typedef __bf16 bf16;
typedef __bf16 bf16x8 __attribute__((ext_vector_type(8)));
typedef float  f32x4v __attribute__((ext_vector_type(4)));

// ---------------------------------------------------------------- reductions
__device__ __forceinline__ float block_reduce_sum256(float v) {
    __shared__ float red[256];
    int tid = threadIdx.x;
    red[tid] = v; __syncthreads();
    #pragma unroll
    for (int s = 128; s > 0; s >>= 1) {
        if (tid < s) red[tid] += red[tid + s];
        __syncthreads();
    }
    float r = red[0]; __syncthreads();
    return r;
}

__device__ __forceinline__ float block_reduce_max256(float v) {
    __shared__ float redm[256];
    int tid = threadIdx.x;
    redm[tid] = v; __syncthreads();
    #pragma unroll
    for (int s = 128; s > 0; s >>= 1) {
        if (tid < s) redm[tid] = fmaxf(redm[tid], redm[tid + s]);
        __syncthreads();
    }
    float r = redm[0]; __syncthreads();
    return r;
}

// ---------------------------------------------------------------- bf16x3 split-MFMA GEMM
// C[M x N] = act(alpha * A @ B + bias), fp32 in/out, fp32-like precision via
// hi/lo bf16 split (3 MFMAs per tile pair; missing lo*lo term ~2^-18 rel).
// A [M][K] f32 row-major. B: BNAT ? natural [K][N] : transposed [N][K].
// Tile 128x128, TK=32, 256 threads (4 waves 2x2), 16x16x32 bf16 MFMA.
// z-batching: zb = z / nsplit applies sAz/sBz/sCz; zs = z % nsplit gives
// K-range [zs*KS, (zs+1)*KS) (split-K => ATOMIC accumulate into zeroed C).
template<bool RELU, bool TRANS, bool ATOMIC, bool BNAT>
__global__ __launch_bounds__(256, 2)
void gemm3(const float* __restrict__ A, const float* __restrict__ B,
           const float* __restrict__ bias, float* __restrict__ C,
           int K, int lda, int ldb, int ldc, float alpha,
           long sAz, long sBz, long sCz, int nsplit, int KS)
{
    constexpr int BM = 128, BN = 128, TK = 32;
    __shared__ __align__(16) bf16 Ah[BM * TK];
    __shared__ __align__(16) bf16 Al[BM * TK];
    __shared__ __align__(16) bf16 Bh[BN * TK];
    __shared__ __align__(16) bf16 Bl[BN * TK];

    const int tid  = threadIdx.x;
    const int wave = tid >> 6, lane = tid & 63;
    const int wr = wave >> 1, wc = wave & 1;
    const long bm = (long)blockIdx.y * BM;
    const long bn = (long)blockIdx.x * BN;
    const int zb = blockIdx.z / nsplit, zs = blockIdx.z % nsplit;
    A += (long)zb * sAz;  B += (long)zb * sBz;  C += (long)zb * sCz;

    const int srow = tid >> 1, skh = (tid & 1) * 16;   // A staging: 2 thr/row, 16 k each
    const int bncol = tid & 127, bkh = (tid >> 7) * 16; // BNAT staging: 2 thr/col
    const int fr = lane & 15, fq = lane >> 4;

    f32x4v acc[4][4] = {};

    const int kbeg = zs * KS, kend = kbeg + KS;
    for (int k0 = kbeg; k0 < kend; k0 += TK) {
        // ---- stage A (hi/lo)
        {
            const float* src = A + (bm + srow) * (long)lda + k0 + skh;
            float v[16];
            #pragma unroll
            for (int q = 0; q < 4; q++) {
                float4 f = ((const float4*)src)[q];
                v[q*4+0] = f.x; v[q*4+1] = f.y; v[q*4+2] = f.z; v[q*4+3] = f.w;
            }
            bf16 h[16], l[16];
            #pragma unroll
            for (int q = 0; q < 16; q++) {
                bf16 hh = (bf16)v[q]; h[q] = hh; l[q] = (bf16)(v[q] - (float)hh);
            }
            bf16* hd = &Ah[srow * TK + skh];
            bf16* ld_ = &Al[srow * TK + skh];
            ((bf16x8*)hd)[0] = *(bf16x8*)&h[0]; ((bf16x8*)hd)[1] = *(bf16x8*)&h[8];
            ((bf16x8*)ld_)[0] = *(bf16x8*)&l[0]; ((bf16x8*)ld_)[1] = *(bf16x8*)&l[8];
        }
        // ---- stage B (hi/lo)
        if (BNAT) {
            const float* src = B + (long)(k0 + bkh) * ldb + bn + bncol;
            bf16 h[16], l[16];
            #pragma unroll
            for (int kk = 0; kk < 16; kk++) {
                float v = src[(long)kk * ldb];
                bf16 hh = (bf16)v; h[kk] = hh; l[kk] = (bf16)(v - (float)hh);
            }
            bf16* hd = &Bh[bncol * TK + bkh];
            bf16* ld_ = &Bl[bncol * TK + bkh];
            ((bf16x8*)hd)[0] = *(bf16x8*)&h[0]; ((bf16x8*)hd)[1] = *(bf16x8*)&h[8];
            ((bf16x8*)ld_)[0] = *(bf16x8*)&l[0]; ((bf16x8*)ld_)[1] = *(bf16x8*)&l[8];
        } else {
            const float* src = B + (bm * 0 + (long)(bn + srow)) * (long)ldb + k0 + skh;
            float v[16];
            #pragma unroll
            for (int q = 0; q < 4; q++) {
                float4 f = ((const float4*)src)[q];
                v[q*4+0] = f.x; v[q*4+1] = f.y; v[q*4+2] = f.z; v[q*4+3] = f.w;
            }
            bf16 h[16], l[16];
            #pragma unroll
            for (int q = 0; q < 16; q++) {
                bf16 hh = (bf16)v[q]; h[q] = hh; l[q] = (bf16)(v[q] - (float)hh);
            }
            bf16* hd = &Bh[srow * TK + skh];
            bf16* ld_ = &Bl[srow * TK + skh];
            ((bf16x8*)hd)[0] = *(bf16x8*)&h[0]; ((bf16x8*)hd)[1] = *(bf16x8*)&h[8];
            ((bf16x8*)ld_)[0] = *(bf16x8*)&l[0]; ((bf16x8*)ld_)[1] = *(bf16x8*)&l[8];
        }
        __syncthreads();

        bf16x8 ah[4], al[4], bh[4], bl[4];
        #pragma unroll
        for (int i = 0; i < 4; i++) {
            const int r = (wr * 64 + i * 16 + fr) * TK + fq * 8;
            ah[i] = *(const bf16x8*)&Ah[r];
            al[i] = *(const bf16x8*)&Al[r];
        }
        #pragma unroll
        for (int j = 0; j < 4; j++) {
            const int r = (wc * 64 + j * 16 + fr) * TK + fq * 8;
            bh[j] = *(const bf16x8*)&Bh[r];
            bl[j] = *(const bf16x8*)&Bl[r];
        }
        #pragma unroll
        for (int i = 0; i < 4; i++)
            #pragma unroll
            for (int j = 0; j < 4; j++) {
                acc[i][j] = __builtin_amdgcn_mfma_f32_16x16x32_bf16(al[i], bh[j], acc[i][j], 0, 0, 0);
                acc[i][j] = __builtin_amdgcn_mfma_f32_16x16x32_bf16(ah[i], bl[j], acc[i][j], 0, 0, 0);
                acc[i][j] = __builtin_amdgcn_mfma_f32_16x16x32_bf16(ah[i], bh[j], acc[i][j], 0, 0, 0);
            }
        __syncthreads();
    }

    #pragma unroll
    for (int i = 0; i < 4; i++) {
        #pragma unroll
        for (int j = 0; j < 4; j++) {
            const long col = bn + wc * 64 + j * 16 + fr;
            const float bv = bias ? bias[col] : 0.f;
            #pragma unroll
            for (int r = 0; r < 4; r++) {
                const long row = bm + wr * 64 + i * 16 + fq * 4 + r;
                float v = acc[i][j][r] * alpha + bv;
                if (RELU) v = fmaxf(v, 0.f);
                if (ATOMIC)      atomicAdd(&C[row * (long)ldc + col], v);
                else if (TRANS)  C[col * (long)ldc + row] = v;
                else             C[row * (long)ldc + col] = v;
            }
        }
    }
}

// ---------------------------------------------------------------- softmax rows in-place (f32), ncols = 4096
__global__ void softmax_rows_f32(float* __restrict__ S)
{
    const long row = blockIdx.x;
    const int tid = threadIdx.x;
    float* s = S + row * 4096L;
    float ev[16];
    float m = -1e30f;
    #pragma unroll
    for (int i = 0; i < 16; i++) { ev[i] = s[tid + (i << 8)]; m = fmaxf(m, ev[i]); }
    m = block_reduce_max256(m);
    float sum = 0.f;
    #pragma unroll
    for (int i = 0; i < 16; i++) { ev[i] = __expf(ev[i] - m); sum += ev[i]; }
    sum = block_reduce_sum256(sum);
    const float inv = 1.f / sum;
    #pragma unroll
    for (int i = 0; i < 16; i++) s[tid + (i << 8)] = ev[i] * inv;
}

// ---------------------------------------------------------------- residual + layernorm (f32, D=512)
__global__ void add_ln_f32(const float* __restrict__ a, const float* __restrict__ b,
                           const float* __restrict__ g, const float* __restrict__ be,
                           float* __restrict__ out)
{
    const long row = blockIdx.x;
    const int tid = threadIdx.x;
    const long base = row * 512L;
    float x0 = a[base + tid]       + b[base + tid];
    float x1 = a[base + tid + 256] + b[base + tid + 256];
    float s = block_reduce_sum256(x0 + x1);
    float mu = s * (1.f / 512.f);
    float d0 = x0 - mu, d1 = x1 - mu;
    float var = block_reduce_sum256(d0 * d0 + d1 * d1) * (1.f / 512.f);
    float invs = rsqrtf(var + 1e-6f);
    out[base + tid]       = d0 * invs * g[tid]       + be[tid];
    out[base + tid + 256] = d1 * invs * g[tid + 256] + be[tid + 256];
}

// ---------------------------------------------------------------- normalize emb rows (f32, E=512)
__global__ void normalize_emb(const float* __restrict__ emb, float* __restrict__ embn)
{
    const long row = blockIdx.x;
    const int tid = threadIdx.x;
    const long base = row * 512L;
    float a0 = emb[base + tid];
    float a1 = emb[base + tid + 256];
    float ss = block_reduce_sum256(a0 * a0 + a1 * a1);
    float sc = rsqrtf(fmaxf(ss, 1e-12f));
    embn[base + tid]       = a0 * sc;
    embn[base + tid + 256] = a1 * sc;
}

// ---------------------------------------------------------------- VQ: argmax over sims row -> one-hot in place + gather vq_feat
__global__ void vq_select_onehot(float* __restrict__ sims, const float* __restrict__ emb,
                                 float* __restrict__ vq_out)
{
    __shared__ float sv[256];
    __shared__ int   si[256];
    const long row = blockIdx.x;
    const int tid = threadIdx.x;
    float* s = sims + row * 1024L;
    float v0 = s[tid], v1 = s[tid + 256], v2 = s[tid + 512], v3 = s[tid + 768];
    float best = v0; int bi = tid;
    if (v1 > best) { best = v1; bi = tid + 256; }
    if (v2 > best) { best = v2; bi = tid + 512; }
    if (v3 > best) { best = v3; bi = tid + 768; }
    sv[tid] = best; si[tid] = bi; __syncthreads();
    #pragma unroll
    for (int st = 128; st > 0; st >>= 1) {
        if (tid < st) {
            if (sv[tid + st] > sv[tid] ||
                (sv[tid + st] == sv[tid] && si[tid + st] < si[tid])) {
                sv[tid] = sv[tid + st]; si[tid] = si[tid + st];
            }
        }
        __syncthreads();
    }
    const int idx = si[0];
    s[tid]       = (tid       == idx) ? 1.f : 0.f;
    s[tid + 256] = (tid + 256 == idx) ? 1.f : 0.f;
    s[tid + 512] = (tid + 512 == idx) ? 1.f : 0.f;
    s[tid + 768] = (tid + 768 == idx) ? 1.f : 0.f;
    const float* er = emb + (long)idx * 512;
    float* vr = vq_out + row * 512L;
    vr[tid]       = er[tid];
    vr[tid + 256] = er[tid + 256];
}

// ---------------------------------------------------------------- host side
struct EncW {
    const float *wq, *wk, *wv, *wo, *w1, *w2;      // natural [K][N] layouts
    const float *bq, *bk, *bv, *bo, *b1, *b2;
    const float *g1, *be1, *g2, *be2;
};

static void run_encoder_g3(hipStream_t stream, const float* x, const EncW& w,
                           float* qb, float* kb, float* vt, float* ctx,
                           float* S_all, float* out)
{
    const int N = 4096, D = 512, DH = 128, CH = 512;
    const float isq = 0.08838834764831843f;  // 1/sqrt(128)
    // q, k (B natural), v stored transposed vt[d][n]
    gemm3<false, false, false, true><<<dim3(4, 32, 1), 256, 0, stream>>>(
        x, w.wq, w.bq, qb, D, D, D, D, 1.f, 0, 0, 0, 1, D);
    gemm3<false, false, false, true><<<dim3(4, 32, 1), 256, 0, stream>>>(
        x, w.wk, w.bk, kb, D, D, D, D, 1.f, 0, 0, 0, 1, D);
    gemm3<false, true, false, true><<<dim3(4, 32, 1), 256, 0, stream>>>(
        x, w.wv, w.bv, vt, D, D, D, N, 1.f, 0, 0, 0, 1, D);
    hipMemsetAsync(ctx, 0, (size_t)N * D * sizeof(float), stream);
    for (int c = 0; c < N / CH; c++) {
        // S_all[h][CH][N] = (Q_h[chunk] K_h^T)/sqrt(dh)
        gemm3<false, false, false, false><<<dim3(N / 128, CH / 128, 4), 256, 0, stream>>>(
            qb + (size_t)c * CH * D, kb, nullptr, S_all,
            DH, D, D, N, isq, DH, DH, (long)CH * N, 1, DH);
        softmax_rows_f32<<<4 * CH, 256, 0, stream>>>(S_all);
        // ctx[chunk] += P_h @ V_h (split-K=8, atomic into zeroed ctx)
        gemm3<false, false, true, false><<<dim3(1, CH / 128, 32), 256, 0, stream>>>(
            S_all, vt, nullptr, ctx + (size_t)c * CH * D,
            N, N, N, D, 1.f, (long)CH * N, (long)DH * N, DH, 8, N / 8);
    }
    // wo projection, LN1, FFN, LN2
    gemm3<false, false, false, true><<<dim3(4, 32, 1), 256, 0, stream>>>(
        ctx, w.wo, w.bo, qb, D, D, D, D, 1.f, 0, 0, 0, 1, D);
    add_ln_f32<<<N, 256, 0, stream>>>(x, qb, w.g1, w.be1, vt);        // x1 -> vt
    gemm3<true, false, false, true><<<dim3(4, 32, 1), 256, 0, stream>>>(
        vt, w.w1, w.b1, kb, D, D, D, D, 1.f, 0, 0, 0, 1, D);
    gemm3<false, false, false, true><<<dim3(4, 32, 1), 256, 0, stream>>>(
        kb, w.w2, w.b2, qb, D, D, D, D, 1.f, 0, 0, 0, 1, D);
    add_ln_f32<<<N, 256, 0, stream>>>(vt, qb, w.g2, w.be2, out);
}

extern "C" void kernel_launch(void* const* d_in, const int* in_sizes, int n_in,
                              void* d_out, int out_size, void* d_ws, size_t ws_size,
                              hipStream_t stream)
{
    const int N = 4096, D = 512, E = 512, F = 4096, KCB = 1024;
    (void)in_sizes; (void)n_in; (void)out_size; (void)d_ws; (void)ws_size;

    const float* x_in  = (const float*)d_in[0];
    const float* fc1_w = (const float*)d_in[33];
    const float* fc1_b = (const float*)d_in[34];
    const float* fc2_w = (const float*)d_in[35];
    const float* fc2_b = (const float*)d_in[36];
    const float* emb   = (const float*)d_in[37];

    // ---- output regions (f32); context_ind = one-hot [N, K]
    float* out0 = (float*)d_out;                  // encoded [N,E]       8 MB
    float* out1 = out0 + (size_t)N * E;           // vq_feat [N,E]       8 MB
    float* out2 = out1 + (size_t)N * E;           // one_hot [N,K]      16 MB
    float* out3 = out2 + (size_t)N * KCB;         // decoded [N,F]      64 MB
    float* out4 = out3 + (size_t)N * F;           // emb copy [K,E]      2 MB

    // ---- arena inside out3 (64 MB); dead before the fc2 writes reach it
    char* arena = (char*)out3;
    const size_t MB = 1024 * 1024;
    float* qb     = (float*)(arena + 0 * MB);     // [0,8)
    float* kb     = (float*)(arena + 8 * MB);     // [8,16)
    float* vt     = (float*)(arena + 16 * MB);    // [16,24)
    float* ctx    = (float*)(arena + 24 * MB);    // [24,32)
    float* S_all  = (float*)(arena + 32 * MB);    // [32,64): 4 x 512 x 4096 f32
    float* decout = (float*)(arena + 56 * MB);    // [56,64): written only after S_all dead
    float* embn   = out1;                         // 2 MB of vq_feat region (dead until vq_select)
    float* stage  = (float*)out4;                 // 2 MB staging (emb copied last)

    EncW ew = { (const float*)d_in[1],  (const float*)d_in[2],  (const float*)d_in[3],
                (const float*)d_in[4],  (const float*)d_in[5],  (const float*)d_in[6],
                (const float*)d_in[7],  (const float*)d_in[8],  (const float*)d_in[9],
                (const float*)d_in[10], (const float*)d_in[11], (const float*)d_in[12],
                (const float*)d_in[13], (const float*)d_in[14], (const float*)d_in[15],
                (const float*)d_in[16] };
    EncW dw = { (const float*)d_in[17], (const float*)d_in[18], (const float*)d_in[19],
                (const float*)d_in[20], (const float*)d_in[21], (const float*)d_in[22],
                (const float*)d_in[23], (const float*)d_in[24], (const float*)d_in[25],
                (const float*)d_in[26], (const float*)d_in[27], (const float*)d_in[28],
                (const float*)d_in[29], (const float*)d_in[30], (const float*)d_in[31],
                (const float*)d_in[32] };

    // ---- phase E: encoder, output -> ctx
    normalize_emb<<<KCB, 256, 0, stream>>>(emb, embn);
    run_encoder_g3(stream, x_in, ew, qb, kb, vt, ctx, S_all, ctx);

    // ---- phase F: fc1 -> encoded (out0)
    gemm3<false, false, false, true><<<dim3(4, 32, 1), 256, 0, stream>>>(
        ctx, fc1_w, fc1_b, out0, D, D, E, E, 1.f, 0, 0, 0, 1, D);

    // ---- phase V: sims = encoded @ embn^T into out2; argmax -> one-hot in place + gather
    gemm3<false, false, false, false><<<dim3(8, 32, 1), 256, 0, stream>>>(
        out0, embn, nullptr, out2, E, E, E, KCB, 1.f, 0, 0, 0, 1, E);
    vq_select_onehot<<<N, 256, 0, stream>>>(out2, emb, out1);

    // ---- phase D: decoder, input = out1 (vq_feat), output -> decout [56,64)
    run_encoder_g3(stream, out1, dw, qb, kb, vt, ctx, S_all, decout);

    // ---- phase G: fc2 + relu, B natural (no transpose needed).
    // Rows [0,3584) write out3 [0,56M) — disjoint from decout [56,64).
    // Rows [3584,4096) staged into out4 first, since their writes cover decout.
    hipMemcpyAsync(stage, decout + (size_t)3584 * D, (size_t)512 * D * sizeof(float),
                   hipMemcpyDeviceToDevice, stream);
    gemm3<true, false, false, true><<<dim3(F / 128, 3584 / 128, 1), 256, 0, stream>>>(
        decout, fc2_w, fc2_b, out3, D, D, F, F, 1.f, 0, 0, 0, 1, D);
    gemm3<true, false, false, true><<<dim3(F / 128, 512 / 128, 1), 256, 0, stream>>>(
        stage, fc2_w, fc2_b, out3 + (size_t)3584 * F, D, D, F, F, 1.f, 0, 0, 0, 1, D);

    // ---- emb copy last (out4 was staging)
    hipMemcpyAsync(out4, emb, (size_t)KCB * E * sizeof(float), hipMemcpyDeviceToDevice, stream);
}

// Round 7
// 1393.339 us; speedup vs baseline: 2.3523x; 1.3337x over previous
//
#include <hip/hip_runtime.h>
#include <hip/hip_bf16.h>
#include <stdint.h>

typedef __bf16 bf16;
typedef __bf16 bf16x8 __attribute__((ext_vector_type(8)));
typedef float  f32x4v __attribute__((ext_vector_type(4)));

// ---------------------------------------------------------------- reductions
__device__ __forceinline__ float block_reduce_sum256(float v) {
    __shared__ float red[256];
    int tid = threadIdx.x;
    red[tid] = v; __syncthreads();
    #pragma unroll
    for (int s = 128; s > 0; s >>= 1) {
        if (tid < s) red[tid] += red[tid + s];
        __syncthreads();
    }
    float r = red[0]; __syncthreads();
    return r;
}

// ---------------------------------------------------------------- bf16x3 split-MFMA GEMM
// C[M x N] = act(alpha * A @ B + bias), fp32 in/out, fp32-like precision via
// hi/lo bf16 split. A [M][K] f32 row-major. B: BNAT ? [K][N] : [N][K].
template<bool RELU, bool TRANS, bool ATOMIC, bool BNAT>
__global__ __launch_bounds__(256, 2)
void gemm3(const float* __restrict__ A, const float* __restrict__ B,
           const float* __restrict__ bias, float* __restrict__ C,
           int K, int lda, int ldb, int ldc, float alpha,
           long sAz, long sBz, long sCz, int nsplit, int KS)
{
    constexpr int BM = 128, BN = 128, TK = 32;
    __shared__ __align__(16) bf16 Ah[BM * TK];
    __shared__ __align__(16) bf16 Al[BM * TK];
    __shared__ __align__(16) bf16 Bh[BN * TK];
    __shared__ __align__(16) bf16 Bl[BN * TK];

    const int tid  = threadIdx.x;
    const int wave = tid >> 6, lane = tid & 63;
    const int wr = wave >> 1, wc = wave & 1;
    const long bm = (long)blockIdx.y * BM;
    const long bn = (long)blockIdx.x * BN;
    const int zb = blockIdx.z / nsplit, zs = blockIdx.z % nsplit;
    A += (long)zb * sAz;  B += (long)zb * sBz;  C += (long)zb * sCz;

    const int srow = tid >> 1, skh = (tid & 1) * 16;
    const int bncol = tid & 127, bkh = (tid >> 7) * 16;
    const int fr = lane & 15, fq = lane >> 4;

    f32x4v acc[4][4] = {};

    const int kbeg = zs * KS, kend = kbeg + KS;
    for (int k0 = kbeg; k0 < kend; k0 += TK) {
        {
            const float* src = A + (bm + srow) * (long)lda + k0 + skh;
            float v[16];
            #pragma unroll
            for (int q = 0; q < 4; q++) {
                float4 f = ((const float4*)src)[q];
                v[q*4+0] = f.x; v[q*4+1] = f.y; v[q*4+2] = f.z; v[q*4+3] = f.w;
            }
            bf16 h[16], l[16];
            #pragma unroll
            for (int q = 0; q < 16; q++) {
                bf16 hh = (bf16)v[q]; h[q] = hh; l[q] = (bf16)(v[q] - (float)hh);
            }
            bf16* hd = &Ah[srow * TK + skh];
            bf16* ld_ = &Al[srow * TK + skh];
            ((bf16x8*)hd)[0] = *(bf16x8*)&h[0]; ((bf16x8*)hd)[1] = *(bf16x8*)&h[8];
            ((bf16x8*)ld_)[0] = *(bf16x8*)&l[0]; ((bf16x8*)ld_)[1] = *(bf16x8*)&l[8];
        }
        if (BNAT) {
            const float* src = B + (long)(k0 + bkh) * ldb + bn + bncol;
            bf16 h[16], l[16];
            #pragma unroll
            for (int kk = 0; kk < 16; kk++) {
                float v = src[(long)kk * ldb];
                bf16 hh = (bf16)v; h[kk] = hh; l[kk] = (bf16)(v - (float)hh);
            }
            bf16* hd = &Bh[bncol * TK + bkh];
            bf16* ld_ = &Bl[bncol * TK + bkh];
            ((bf16x8*)hd)[0] = *(bf16x8*)&h[0]; ((bf16x8*)hd)[1] = *(bf16x8*)&h[8];
            ((bf16x8*)ld_)[0] = *(bf16x8*)&l[0]; ((bf16x8*)ld_)[1] = *(bf16x8*)&l[8];
        } else {
            const float* src = B + (long)(bn + srow) * (long)ldb + k0 + skh;
            float v[16];
            #pragma unroll
            for (int q = 0; q < 4; q++) {
                float4 f = ((const float4*)src)[q];
                v[q*4+0] = f.x; v[q*4+1] = f.y; v[q*4+2] = f.z; v[q*4+3] = f.w;
            }
            bf16 h[16], l[16];
            #pragma unroll
            for (int q = 0; q < 16; q++) {
                bf16 hh = (bf16)v[q]; h[q] = hh; l[q] = (bf16)(v[q] - (float)hh);
            }
            bf16* hd = &Bh[srow * TK + skh];
            bf16* ld_ = &Bl[srow * TK + skh];
            ((bf16x8*)hd)[0] = *(bf16x8*)&h[0]; ((bf16x8*)hd)[1] = *(bf16x8*)&h[8];
            ((bf16x8*)ld_)[0] = *(bf16x8*)&l[0]; ((bf16x8*)ld_)[1] = *(bf16x8*)&l[8];
        }
        __syncthreads();

        bf16x8 ah[4], al[4], bh[4], bl[4];
        #pragma unroll
        for (int i = 0; i < 4; i++) {
            const int r = (wr * 64 + i * 16 + fr) * TK + fq * 8;
            ah[i] = *(const bf16x8*)&Ah[r];
            al[i] = *(const bf16x8*)&Al[r];
        }
        #pragma unroll
        for (int j = 0; j < 4; j++) {
            const int r = (wc * 64 + j * 16 + fr) * TK + fq * 8;
            bh[j] = *(const bf16x8*)&Bh[r];
            bl[j] = *(const bf16x8*)&Bl[r];
        }
        #pragma unroll
        for (int i = 0; i < 4; i++)
            #pragma unroll
            for (int j = 0; j < 4; j++) {
                acc[i][j] = __builtin_amdgcn_mfma_f32_16x16x32_bf16(al[i], bh[j], acc[i][j], 0, 0, 0);
                acc[i][j] = __builtin_amdgcn_mfma_f32_16x16x32_bf16(ah[i], bl[j], acc[i][j], 0, 0, 0);
                acc[i][j] = __builtin_amdgcn_mfma_f32_16x16x32_bf16(ah[i], bh[j], acc[i][j], 0, 0, 0);
            }
        __syncthreads();
    }

    #pragma unroll
    for (int i = 0; i < 4; i++) {
        #pragma unroll
        for (int j = 0; j < 4; j++) {
            const long col = bn + wc * 64 + j * 16 + fr;
            const float bv = bias ? bias[col] : 0.f;
            #pragma unroll
            for (int r = 0; r < 4; r++) {
                const long row = bm + wr * 64 + i * 16 + fq * 4 + r;
                float v = acc[i][j][r] * alpha + bv;
                if (RELU) v = fmaxf(v, 0.f);
                if (ATOMIC)      atomicAdd(&C[row * (long)ldc + col], v);
                else if (TRANS)  C[col * (long)ldc + row] = v;
                else             C[row * (long)ldc + col] = v;
            }
        }
    }
}

// ---------------------------------------------------------------- fused flash attention
// Q,K [N][D] f32 (head h at cols h*128..h*128+127), Vt [D][N] f32 (V transposed).
// O [N][D] f32 = softmax(Q_h K_h^T / sqrt(128)) V_h per head.
// Grid (64, 4): lin swizzled so consecutive-dispatch blocks share a head (XCD L2 reuse).
// BQ=64 rows/block, BK=64 KV cols/iter. bf16 hi/lo everywhere (bf16x3 MFMA).
__global__ __launch_bounds__(256, 2)
void flash_attn(const float* __restrict__ Q, const float* __restrict__ K,
                const float* __restrict__ Vt, float* __restrict__ O)
{
    constexpr int N = 4096, D = 512;
    constexpr float TS = 0.12751791f;   // (1/sqrt(128)) * log2(e)
    constexpr int PSTR = 68;

    __shared__ __align__(16) bf16 smem[32768];   // 64 KB exactly
    bf16* Kh = smem;                 // [64][128], XOR-swizzled chunks of 8
    bf16* Kl = smem + 8192;
    bf16* Vh = smem + 16384;         // [128][64], XOR-swizzled
    bf16* Vl = smem + 24576;
    float* Pf  = (float*)smem;       // [64][68] f32, aliased over Kh/Kl (dead by then)
    float* xch = (float*)smem + 4352; // 128 floats, after Pf

    const int tid = threadIdx.x;
    const int wave = tid >> 6, lane = tid & 63;
    const int wr = wave >> 1, wc = wave & 1;
    const int fr = lane & 15, fq = lane >> 4;

    const int lin = blockIdx.y * 64 + blockIdx.x;
    const int h  = lin & 3;                          // same-h blocks land on same XCD
    const int qt = (lin >> 3) + 32 * ((lin >> 2) & 1);
    const long q0 = (long)qt * 64;

    // preload Q fragments (hi/lo): rows wr*32+i*16+fr, k = kt*32+fq*8+j
    bf16x8 qh[2][4], ql[2][4];
    #pragma unroll
    for (int i = 0; i < 2; i++)
        #pragma unroll
        for (int kt = 0; kt < 4; kt++) {
            const float* src = Q + (q0 + wr*32 + i*16 + fr) * D + h*128 + kt*32 + fq*8;
            float4 f0 = ((const float4*)src)[0];
            float4 f1 = ((const float4*)src)[1];
            float v[8] = {f0.x,f0.y,f0.z,f0.w,f1.x,f1.y,f1.z,f1.w};
            bf16x8 hh, ll;
            #pragma unroll
            for (int j = 0; j < 8; j++) {
                bf16 b = (bf16)v[j]; hh[j] = b; ll[j] = (bf16)(v[j] - (float)b);
            }
            qh[i][kt] = hh; ql[i][kt] = ll;
        }

    f32x4v o[2][4] = {};
    float m_run[2][4], l_run[2][4];
    #pragma unroll
    for (int i = 0; i < 2; i++)
        #pragma unroll
        for (int r = 0; r < 4; r++) { m_run[i][r] = -1e30f; l_run[i][r] = 0.f; }

    for (int j0 = 0; j0 < N; j0 += 64) {
        __syncthreads();   // A: previous PV reads of P/V done before restaging
        // ---- stage K tile (64 kv-rows x 128 dh), chunks of 8, swizzled
        #pragma unroll
        for (int g = 0; g < 4; g++) {
            const int cid = g * 256 + tid;
            const int n = cid >> 4, k8 = cid & 15;
            const float* src = K + (long)(j0 + n) * D + h*128 + k8*8;
            float4 f0 = ((const float4*)src)[0];
            float4 f1 = ((const float4*)src)[1];
            float v[8] = {f0.x,f0.y,f0.z,f0.w,f1.x,f1.y,f1.z,f1.w};
            bf16x8 hh, ll;
            #pragma unroll
            for (int j = 0; j < 8; j++) {
                bf16 b = (bf16)v[j]; hh[j] = b; ll[j] = (bf16)(v[j] - (float)b);
            }
            const int off = n*128 + ((k8 ^ (n & 15)) << 3);
            *(bf16x8*)&Kh[off] = hh;
            *(bf16x8*)&Kl[off] = ll;
        }
        // ---- stage V tile (128 dh x 64 kv) from Vt, swizzled
        #pragma unroll
        for (int g = 0; g < 4; g++) {
            const int cid = g * 256 + tid;
            const int d = cid >> 3, k8 = cid & 7;
            const float* src = Vt + (long)(h*128 + d) * N + j0 + k8*8;
            float4 f0 = ((const float4*)src)[0];
            float4 f1 = ((const float4*)src)[1];
            float v[8] = {f0.x,f0.y,f0.z,f0.w,f1.x,f1.y,f1.z,f1.w};
            bf16x8 hh, ll;
            #pragma unroll
            for (int j = 0; j < 8; j++) {
                bf16 b = (bf16)v[j]; hh[j] = b; ll[j] = (bf16)(v[j] - (float)b);
            }
            const int off = d*64 + ((k8 ^ (d & 7)) << 3);
            *(bf16x8*)&Vh[off] = hh;
            *(bf16x8*)&Vl[off] = ll;
        }
        __syncthreads();   // B: staging visible

        // ---- S = Q K^T (bf16x3), 64x64 tile, this wave: rows wr*32+, cols wc*32+
        f32x4v s[2][2] = {};
        {
            bf16x8 kh[2][4], kl[2][4];
            #pragma unroll
            for (int jb = 0; jb < 2; jb++)
                #pragma unroll
                for (int kt = 0; kt < 4; kt++) {
                    const int col = wc*32 + jb*16 + fr;
                    const int k8 = kt*4 + fq;
                    const int off = col*128 + ((k8 ^ (col & 15)) << 3);
                    kh[jb][kt] = *(const bf16x8*)&Kh[off];
                    kl[jb][kt] = *(const bf16x8*)&Kl[off];
                }
            #pragma unroll
            for (int i = 0; i < 2; i++)
                #pragma unroll
                for (int jb = 0; jb < 2; jb++)
                    #pragma unroll
                    for (int kt = 0; kt < 4; kt++) {
                        s[i][jb] = __builtin_amdgcn_mfma_f32_16x16x32_bf16(ql[i][kt], kh[jb][kt], s[i][jb], 0, 0, 0);
                        s[i][jb] = __builtin_amdgcn_mfma_f32_16x16x32_bf16(qh[i][kt], kl[jb][kt], s[i][jb], 0, 0, 0);
                        s[i][jb] = __builtin_amdgcn_mfma_f32_16x16x32_bf16(qh[i][kt], kh[jb][kt], s[i][jb], 0, 0, 0);
                    }
        }

        // ---- online softmax (t = score * TS, exp2 domain)
        float t0[2][2][4], mloc[2][4];
        #pragma unroll
        for (int i = 0; i < 2; i++)
            #pragma unroll
            for (int r = 0; r < 4; r++) {
                float a = s[i][0][r] * TS, b = s[i][1][r] * TS;
                t0[i][0][r] = a; t0[i][1][r] = b;
                mloc[i][r] = fmaxf(a, b);
            }
        #pragma unroll
        for (int b = 1; b <= 8; b <<= 1)
            #pragma unroll
            for (int i = 0; i < 2; i++)
                #pragma unroll
                for (int r = 0; r < 4; r++)
                    mloc[i][r] = fmaxf(mloc[i][r], __shfl_xor(mloc[i][r], b));
        #pragma unroll
        for (int i = 0; i < 2; i++)
            #pragma unroll
            for (int r = 0; r < 4; r++)
                xch[wc*64 + wr*32 + i*16 + fq*4 + r] = mloc[i][r];
        __syncthreads();   // C: max exchange visible; all K-frag reads consumed

        float alpha[2][4], rs[2][4];
        #pragma unroll
        for (int i = 0; i < 2; i++)
            #pragma unroll
            for (int r = 0; r < 4; r++) {
                const float mo = xch[(1 ^ wc)*64 + wr*32 + i*16 + fq*4 + r];
                const float mn = fmaxf(m_run[i][r], fmaxf(mloc[i][r], mo));
                alpha[i][r] = exp2f(m_run[i][r] - mn);
                m_run[i][r] = mn;
                rs[i][r] = 0.f;
            }
        #pragma unroll
        for (int i = 0; i < 2; i++)
            #pragma unroll
            for (int jb = 0; jb < 2; jb++)
                #pragma unroll
                for (int r = 0; r < 4; r++) {
                    const float p = exp2f(t0[i][jb][r] - m_run[i][r]);
                    Pf[(wr*32 + i*16 + fq*4 + r) * PSTR + wc*32 + jb*16 + fr] = p;
                    rs[i][r] += p;
                }
        #pragma unroll
        for (int b = 1; b <= 8; b <<= 1)
            #pragma unroll
            for (int i = 0; i < 2; i++)
                #pragma unroll
                for (int r = 0; r < 4; r++)
                    rs[i][r] += __shfl_xor(rs[i][r], b);
        #pragma unroll
        for (int i = 0; i < 2; i++)
            #pragma unroll
            for (int r = 0; r < 4; r++)
                l_run[i][r] = l_run[i][r] * alpha[i][r] + rs[i][r];
        #pragma unroll
        for (int i = 0; i < 2; i++)
            #pragma unroll
            for (int jbo = 0; jbo < 4; jbo++)
                #pragma unroll
                for (int r = 0; r < 4; r++)
                    o[i][jbo][r] *= alpha[i][r];
        __syncthreads();   // D: P visible

        // ---- PV (bf16x3): O[64 x 128] += P[64 x 64] V[64 x 128]
        {
            bf16x8 vh[4][2], vl[4][2], ph[2][2], pl[2][2];
            #pragma unroll
            for (int jbo = 0; jbo < 4; jbo++)
                #pragma unroll
                for (int kt = 0; kt < 2; kt++) {
                    const int col = wc*64 + jbo*16 + fr;
                    const int k8 = kt*4 + fq;
                    const int off = col*64 + ((k8 ^ (col & 7)) << 3);
                    vh[jbo][kt] = *(const bf16x8*)&Vh[off];
                    vl[jbo][kt] = *(const bf16x8*)&Vl[off];
                }
            #pragma unroll
            for (int i = 0; i < 2; i++)
                #pragma unroll
                for (int kt = 0; kt < 2; kt++) {
                    const float* base = &Pf[(wr*32 + i*16 + fr) * PSTR + kt*32 + fq*8];
                    float4 f0 = ((const float4*)base)[0];
                    float4 f1 = ((const float4*)base)[1];
                    float v[8] = {f0.x,f0.y,f0.z,f0.w,f1.x,f1.y,f1.z,f1.w};
                    bf16x8 hh, ll;
                    #pragma unroll
                    for (int j = 0; j < 8; j++) {
                        bf16 b = (bf16)v[j]; hh[j] = b; ll[j] = (bf16)(v[j] - (float)b);
                    }
                    ph[i][kt] = hh; pl[i][kt] = ll;
                }
            #pragma unroll
            for (int i = 0; i < 2; i++)
                #pragma unroll
                for (int jbo = 0; jbo < 4; jbo++)
                    #pragma unroll
                    for (int kt = 0; kt < 2; kt++) {
                        o[i][jbo] = __builtin_amdgcn_mfma_f32_16x16x32_bf16(pl[i][kt], vh[jbo][kt], o[i][jbo], 0, 0, 0);
                        o[i][jbo] = __builtin_amdgcn_mfma_f32_16x16x32_bf16(ph[i][kt], vl[jbo][kt], o[i][jbo], 0, 0, 0);
                        o[i][jbo] = __builtin_amdgcn_mfma_f32_16x16x32_bf16(ph[i][kt], vh[jbo][kt], o[i][jbo], 0, 0, 0);
                    }
        }
    }

    // ---- final l exchange + normalized store
    __syncthreads();
    #pragma unroll
    for (int i = 0; i < 2; i++)
        #pragma unroll
        for (int r = 0; r < 4; r++)
            xch[wc*64 + wr*32 + i*16 + fq*4 + r] = l_run[i][r];
    __syncthreads();
    float inv[2][4];
    #pragma unroll
    for (int i = 0; i < 2; i++)
        #pragma unroll
        for (int r = 0; r < 4; r++) {
            const float lt = l_run[i][r] + xch[(1 ^ wc)*64 + wr*32 + i*16 + fq*4 + r];
            inv[i][r] = 1.f / lt;
        }
    #pragma unroll
    for (int i = 0; i < 2; i++)
        #pragma unroll
        for (int jbo = 0; jbo < 4; jbo++)
            #pragma unroll
            for (int r = 0; r < 4; r++) {
                const long row = q0 + wr*32 + i*16 + fq*4 + r;
                const long col = h*128 + wc*64 + jbo*16 + fr;
                O[row * D + col] = o[i][jbo][r] * inv[i][r];
            }
}

// ---------------------------------------------------------------- residual + layernorm (f32, D=512)
__global__ void add_ln_f32(const float* __restrict__ a, const float* __restrict__ b,
                           const float* __restrict__ g, const float* __restrict__ be,
                           float* __restrict__ out)
{
    const long row = blockIdx.x;
    const int tid = threadIdx.x;
    const long base = row * 512L;
    float x0 = a[base + tid]       + b[base + tid];
    float x1 = a[base + tid + 256] + b[base + tid + 256];
    float s = block_reduce_sum256(x0 + x1);
    float mu = s * (1.f / 512.f);
    float d0 = x0 - mu, d1 = x1 - mu;
    float var = block_reduce_sum256(d0 * d0 + d1 * d1) * (1.f / 512.f);
    float invs = rsqrtf(var + 1e-6f);
    out[base + tid]       = d0 * invs * g[tid]       + be[tid];
    out[base + tid + 256] = d1 * invs * g[tid + 256] + be[tid + 256];
}

// ---------------------------------------------------------------- normalize emb rows (f32, E=512)
__global__ void normalize_emb(const float* __restrict__ emb, float* __restrict__ embn)
{
    const long row = blockIdx.x;
    const int tid = threadIdx.x;
    const long base = row * 512L;
    float a0 = emb[base + tid];
    float a1 = emb[base + tid + 256];
    float ss = block_reduce_sum256(a0 * a0 + a1 * a1);
    float sc = rsqrtf(fmaxf(ss, 1e-12f));
    embn[base + tid]       = a0 * sc;
    embn[base + tid + 256] = a1 * sc;
}

// ---------------------------------------------------------------- VQ: argmax -> one-hot in place + gather vq_feat
__global__ void vq_select_onehot(float* __restrict__ sims, const float* __restrict__ emb,
                                 float* __restrict__ vq_out)
{
    __shared__ float sv[256];
    __shared__ int   si[256];
    const long row = blockIdx.x;
    const int tid = threadIdx.x;
    float* s = sims + row * 1024L;
    float v0 = s[tid], v1 = s[tid + 256], v2 = s[tid + 512], v3 = s[tid + 768];
    float best = v0; int bi = tid;
    if (v1 > best) { best = v1; bi = tid + 256; }
    if (v2 > best) { best = v2; bi = tid + 512; }
    if (v3 > best) { best = v3; bi = tid + 768; }
    sv[tid] = best; si[tid] = bi; __syncthreads();
    #pragma unroll
    for (int st = 128; st > 0; st >>= 1) {
        if (tid < st) {
            if (sv[tid + st] > sv[tid] ||
                (sv[tid + st] == sv[tid] && si[tid + st] < si[tid])) {
                sv[tid] = sv[tid + st]; si[tid] = si[tid + st];
            }
        }
        __syncthreads();
    }
    const int idx = si[0];
    s[tid]       = (tid       == idx) ? 1.f : 0.f;
    s[tid + 256] = (tid + 256 == idx) ? 1.f : 0.f;
    s[tid + 512] = (tid + 512 == idx) ? 1.f : 0.f;
    s[tid + 768] = (tid + 768 == idx) ? 1.f : 0.f;
    const float* er = emb + (long)idx * 512;
    float* vr = vq_out + row * 512L;
    vr[tid]       = er[tid];
    vr[tid + 256] = er[tid + 256];
}

// ---------------------------------------------------------------- host side
struct EncW {
    const float *wq, *wk, *wv, *wo, *w1, *w2;      // natural [K][N] layouts
    const float *bq, *bk, *bv, *bo, *b1, *b2;
    const float *g1, *be1, *g2, *be2;
};

static void run_encoder_g3(hipStream_t stream, const float* x, const EncW& w,
                           float* qb, float* kb, float* vt, float* ctx,
                           float* out)
{
    const int N = 4096, D = 512;
    // q, k (B natural), v stored transposed vt[d][n]
    gemm3<false, false, false, true><<<dim3(4, 32, 1), 256, 0, stream>>>(
        x, w.wq, w.bq, qb, D, D, D, D, 1.f, 0, 0, 0, 1, D);
    gemm3<false, false, false, true><<<dim3(4, 32, 1), 256, 0, stream>>>(
        x, w.wk, w.bk, kb, D, D, D, D, 1.f, 0, 0, 0, 1, D);
    gemm3<false, true, false, true><<<dim3(4, 32, 1), 256, 0, stream>>>(
        x, w.wv, w.bv, vt, D, D, D, N, 1.f, 0, 0, 0, 1, D);
    // fused attention -> ctx
    flash_attn<<<dim3(64, 4), 256, 0, stream>>>(qb, kb, vt, ctx);
    // wo projection, LN1, FFN, LN2
    gemm3<false, false, false, true><<<dim3(4, 32, 1), 256, 0, stream>>>(
        ctx, w.wo, w.bo, qb, D, D, D, D, 1.f, 0, 0, 0, 1, D);
    add_ln_f32<<<N, 256, 0, stream>>>(x, qb, w.g1, w.be1, vt);        // x1 -> vt
    gemm3<true, false, false, true><<<dim3(4, 32, 1), 256, 0, stream>>>(
        vt, w.w1, w.b1, kb, D, D, D, D, 1.f, 0, 0, 0, 1, D);
    gemm3<false, false, false, true><<<dim3(4, 32, 1), 256, 0, stream>>>(
        kb, w.w2, w.b2, qb, D, D, D, D, 1.f, 0, 0, 0, 1, D);
    add_ln_f32<<<N, 256, 0, stream>>>(vt, qb, w.g2, w.be2, out);
}

extern "C" void kernel_launch(void* const* d_in, const int* in_sizes, int n_in,
                              void* d_out, int out_size, void* d_ws, size_t ws_size,
                              hipStream_t stream)
{
    const int N = 4096, D = 512, E = 512, F = 4096, KCB = 1024;
    (void)in_sizes; (void)n_in; (void)out_size; (void)d_ws; (void)ws_size;

    const float* x_in  = (const float*)d_in[0];
    const float* fc1_w = (const float*)d_in[33];
    const float* fc1_b = (const float*)d_in[34];
    const float* fc2_w = (const float*)d_in[35];
    const float* fc2_b = (const float*)d_in[36];
    const float* emb   = (const float*)d_in[37];

    // ---- output regions (f32); context_ind = one-hot [N, K]
    float* out0 = (float*)d_out;                  // encoded [N,E]       8 MB
    float* out1 = out0 + (size_t)N * E;           // vq_feat [N,E]       8 MB
    float* out2 = out1 + (size_t)N * E;           // one_hot [N,K]      16 MB
    float* out3 = out2 + (size_t)N * KCB;         // decoded [N,F]      64 MB
    float* out4 = out3 + (size_t)N * F;           // emb copy [K,E]      2 MB

    // ---- arena inside out3 (64 MB); dead before the fc2 writes reach it
    char* arena = (char*)out3;
    const size_t MB = 1024 * 1024;
    float* qb     = (float*)(arena + 0 * MB);     // [0,8)
    float* kb     = (float*)(arena + 8 * MB);     // [8,16)
    float* vt     = (float*)(arena + 16 * MB);    // [16,24)
    float* ctx    = (float*)(arena + 24 * MB);    // [24,32)
    float* decout = (float*)(arena + 56 * MB);    // [56,64)
    float* embn   = out1;                         // 2 MB of vq_feat region (dead until vq_select)
    float* stage  = (float*)out4;                 // 2 MB staging (emb copied last)

    EncW ew = { (const float*)d_in[1],  (const float*)d_in[2],  (const float*)d_in[3],
                (const float*)d_in[4],  (const float*)d_in[5],  (const float*)d_in[6],
                (const float*)d_in[7],  (const float*)d_in[8],  (const float*)d_in[9],
                (const float*)d_in[10], (const float*)d_in[11], (const float*)d_in[12],
                (const float*)d_in[13], (const float*)d_in[14], (const float*)d_in[15],
                (const float*)d_in[16] };
    EncW dw = { (const float*)d_in[17], (const float*)d_in[18], (const float*)d_in[19],
                (const float*)d_in[20], (const float*)d_in[21], (const float*)d_in[22],
                (const float*)d_in[23], (const float*)d_in[24], (const float*)d_in[25],
                (const float*)d_in[26], (const float*)d_in[27], (const float*)d_in[28],
                (const float*)d_in[29], (const float*)d_in[30], (const float*)d_in[31],
                (const float*)d_in[32] };

    // ---- phase E: encoder, output -> ctx
    normalize_emb<<<KCB, 256, 0, stream>>>(emb, embn);
    run_encoder_g3(stream, x_in, ew, qb, kb, vt, ctx, ctx);

    // ---- phase F: fc1 -> encoded (out0)
    gemm3<false, false, false, true><<<dim3(4, 32, 1), 256, 0, stream>>>(
        ctx, fc1_w, fc1_b, out0, D, D, E, E, 1.f, 0, 0, 0, 1, D);

    // ---- phase V: sims = encoded @ embn^T into out2; argmax -> one-hot in place + gather
    gemm3<false, false, false, false><<<dim3(8, 32, 1), 256, 0, stream>>>(
        out0, embn, nullptr, out2, E, E, E, KCB, 1.f, 0, 0, 0, 1, E);
    vq_select_onehot<<<N, 256, 0, stream>>>(out2, emb, out1);

    // ---- phase D: decoder, input = out1 (vq_feat), output -> decout [56,64)
    run_encoder_g3(stream, out1, dw, qb, kb, vt, ctx, decout);

    // ---- phase G: fc2 + relu, B natural. Rows [0,3584) write [0,56M) (disjoint
    // from decout); rows [3584,4096) read a staged copy since their writes cover decout.
    hipMemcpyAsync(stage, decout + (size_t)3584 * D, (size_t)512 * D * sizeof(float),
                   hipMemcpyDeviceToDevice, stream);
    gemm3<true, false, false, true><<<dim3(F / 128, 3584 / 128, 1), 256, 0, stream>>>(
        decout, fc2_w, fc2_b, out3, D, D, F, F, 1.f, 0, 0, 0, 1, D);
    gemm3<true, false, false, true><<<dim3(F / 128, 512 / 128, 1), 256, 0, stream>>>(
        stage, fc2_w, fc2_b, out3 + (size_t)3584 * F, D, D, F, F, 1.f, 0, 0, 0, 1, D);

    // ---- emb copy last (out4 was staging)
    hipMemcpyAsync(out4, emb, (size_t)KCB * E * sizeof(float), hipMemcpyDeviceToDevice, stream);
}

// Round 8
// 1015.957 us; speedup vs baseline: 3.2261x; 1.3715x over previous
//
#include <hip/hip_runtime.h>
#include <hip/hip_bf16.h>
#include <stdint.h>

typedef __bf16 bf16;
typedef __bf16 bf16x8 __attribute__((ext_vector_type(8)));
typedef float  f32x4v __attribute__((ext_vector_type(4)));

__device__ __forceinline__ void cvt8(const float* v, bf16x8& hh, bf16x8& ll) {
    #pragma unroll
    for (int j = 0; j < 8; j++) {
        bf16 b = (bf16)v[j]; hh[j] = b; ll[j] = (bf16)(v[j] - (float)b);
    }
}

// ---------------------------------------------------------------- reductions
__device__ __forceinline__ float block_reduce_sum256(float v) {
    __shared__ float red[256];
    int tid = threadIdx.x;
    red[tid] = v; __syncthreads();
    #pragma unroll
    for (int s = 128; s > 0; s >>= 1) {
        if (tid < s) red[tid] += red[tid + s];
        __syncthreads();
    }
    float r = red[0]; __syncthreads();
    return r;
}

// ---------------------------------------------------------------- bf16x3 split-MFMA GEMM
// C[M x N] = act(alpha * A @ B + bias), fp32 in, fp32-like precision via hi/lo
// bf16 split. A [M][K] f32. B: BNAT ? natural [K][N] : transposed [N][K].
// Tile BMT x 128 (BMT in {64,128}), TK=32, 256 threads.
// HILO: write bf16 hi/lo pair outputs (Chi/Clo) instead of f32 C.
template<int BMT, bool RELU, bool TRANS, bool BNAT, bool HILO>
__global__ __launch_bounds__(256, 2)
void gemm3(const float* __restrict__ A, const float* __restrict__ B,
           const float* __restrict__ bias, float* __restrict__ C,
           bf16* __restrict__ Chi, bf16* __restrict__ Clo,
           int K, int lda, int ldb, int ldc, float alpha)
{
    constexpr int BN = 128, TK = 32;
    constexpr int RM = BMT / 32;
    __shared__ __align__(16) bf16 Ah[BMT * TK];
    __shared__ __align__(16) bf16 Al[BMT * TK];
    __shared__ __align__(16) bf16 Bh[BN * TK];
    __shared__ __align__(16) bf16 Bl[BN * TK];

    const int tid  = threadIdx.x;
    const int wave = tid >> 6, lane = tid & 63;
    const int wr = wave >> 1, wc = wave & 1;
    const long bm = (long)blockIdx.y * BMT;
    const long bn = (long)blockIdx.x * BN;
    const int fr = lane & 15, fq = lane >> 4;

    f32x4v acc[RM][4] = {};

    for (int k0 = 0; k0 < K; k0 += TK) {
        // ---- stage A (chunks of 8 f32 -> hi/lo bf16x8)
        #pragma unroll
        for (int it = 0; it < BMT / 64; it++) {
            const int c = it * 256 + tid;
            const int r = c >> 2, k8 = c & 3;
            const float* src = A + (bm + r) * (long)lda + k0 + k8 * 8;
            float4 f0 = ((const float4*)src)[0], f1 = ((const float4*)src)[1];
            float v[8] = {f0.x, f0.y, f0.z, f0.w, f1.x, f1.y, f1.z, f1.w};
            bf16x8 hh, ll; cvt8(v, hh, ll);
            *(bf16x8*)&Ah[r * TK + k8 * 8] = hh;
            *(bf16x8*)&Al[r * TK + k8 * 8] = ll;
        }
        // ---- stage B
        if (BNAT) {
            const int col = tid & 127, bkh = (tid >> 7) * 16;
            const float* src = B + (long)(k0 + bkh) * ldb + bn + col;
            float v[16];
            #pragma unroll
            for (int kk = 0; kk < 16; kk++) v[kk] = src[(long)kk * ldb];
            bf16x8 h0, l0, h1, l1; cvt8(v, h0, l0); cvt8(v + 8, h1, l1);
            bf16* hd = &Bh[col * TK + bkh];
            bf16* ld_ = &Bl[col * TK + bkh];
            ((bf16x8*)hd)[0] = h0; ((bf16x8*)hd)[1] = h1;
            ((bf16x8*)ld_)[0] = l0; ((bf16x8*)ld_)[1] = l1;
        } else {
            #pragma unroll
            for (int it = 0; it < 2; it++) {
                const int c = it * 256 + tid;
                const int r = c >> 2, k8 = c & 3;
                const float* src = B + (bn + r) * (long)ldb + k0 + k8 * 8;
                float4 f0 = ((const float4*)src)[0], f1 = ((const float4*)src)[1];
                float v[8] = {f0.x, f0.y, f0.z, f0.w, f1.x, f1.y, f1.z, f1.w};
                bf16x8 hh, ll; cvt8(v, hh, ll);
                *(bf16x8*)&Bh[r * TK + k8 * 8] = hh;
                *(bf16x8*)&Bl[r * TK + k8 * 8] = ll;
            }
        }
        __syncthreads();

        bf16x8 ah[RM], am[RM], bh[4], bm_[4];
        #pragma unroll
        for (int i = 0; i < RM; i++) {
            const int r = (wr * (BMT / 2) + i * 16 + fr) * TK + fq * 8;
            ah[i] = *(const bf16x8*)&Ah[r];
            am[i] = *(const bf16x8*)&Al[r];
        }
        #pragma unroll
        for (int j = 0; j < 4; j++) {
            const int r = (wc * 64 + j * 16 + fr) * TK + fq * 8;
            bh[j] = *(const bf16x8*)&Bh[r];
            bm_[j] = *(const bf16x8*)&Bl[r];
        }
        #pragma unroll
        for (int i = 0; i < RM; i++)
            #pragma unroll
            for (int j = 0; j < 4; j++) {
                acc[i][j] = __builtin_amdgcn_mfma_f32_16x16x32_bf16(am[i], bh[j], acc[i][j], 0, 0, 0);
                acc[i][j] = __builtin_amdgcn_mfma_f32_16x16x32_bf16(ah[i], bm_[j], acc[i][j], 0, 0, 0);
                acc[i][j] = __builtin_amdgcn_mfma_f32_16x16x32_bf16(ah[i], bh[j], acc[i][j], 0, 0, 0);
            }
        __syncthreads();
    }

    #pragma unroll
    for (int i = 0; i < RM; i++) {
        #pragma unroll
        for (int j = 0; j < 4; j++) {
            const long col = bn + wc * 64 + j * 16 + fr;
            const float bv = bias ? bias[col] : 0.f;
            #pragma unroll
            for (int r = 0; r < 4; r++) {
                const long row = bm + wr * (BMT / 2) + i * 16 + fq * 4 + r;
                float v = acc[i][j][r] * alpha + bv;
                if (RELU) v = fmaxf(v, 0.f);
                const long idx = TRANS ? (col * (long)ldc + row) : (row * (long)ldc + col);
                if (HILO) {
                    bf16 hh = (bf16)v;
                    Chi[idx] = hh;
                    Clo[idx] = (bf16)(v - (float)hh);
                } else {
                    C[idx] = v;
                }
            }
        }
    }
}

// ---------------------------------------------------------------- fused flash attention (KV-split x2)
// Q [N][512] f32; Khi/Klo [N][512] bf16; Vthi/Vtlo [512][N] bf16 (V^T).
// Block = (qt, h, s): 64 Q-rows, head h, KV range [s*2048, s*2048+2048).
// Each wave owns 16 full S rows -> no cross-wave softmax exchange.
// Outputs unnormalized partial O + (m, l) per row; flash_merge combines.
__global__ __launch_bounds__(256, 2)
void flash_attn(const float* __restrict__ Q,
                const bf16* __restrict__ Khi, const bf16* __restrict__ Klo,
                const bf16* __restrict__ Vthi, const bf16* __restrict__ Vtlo,
                float* __restrict__ Op, float* __restrict__ ml)
{
    constexpr int N = 4096, D = 512, SPAN = 2048;
    constexpr float TS = 0.12751791f;   // (1/sqrt(128)) * log2(e)
    constexpr int PSTR = 72;

    __shared__ __align__(16) bf16 smem[32768];   // 64 KB
    bf16* Kh = smem;                  // [64][128] swizzled
    bf16* Kl = smem + 8192;
    bf16* Vh = smem + 16384;          // [128][64] swizzled
    bf16* Vl = smem + 24576;

    const int tid = threadIdx.x;
    const int wave = tid >> 6, lane = tid & 63;
    const int fr = lane & 15, fq = lane >> 4;
    const int qt = blockIdx.x, h = blockIdx.y, s = blockIdx.z;
    const long q0 = (long)qt * 64;

    bf16* Phi = smem + wave * 1152;          // wave-private [16][72], over K region
    bf16* Plo = smem + 4608 + wave * 1152;

    // ---- preload Q fragments (rows wave*16+fr), f32 -> hi/lo
    bf16x8 qh[4], ql[4];
    #pragma unroll
    for (int kt = 0; kt < 4; kt++) {
        const float* src = Q + (q0 + wave * 16 + fr) * D + h * 128 + kt * 32 + fq * 8;
        float4 f0 = ((const float4*)src)[0], f1 = ((const float4*)src)[1];
        float v[8] = {f0.x, f0.y, f0.z, f0.w, f1.x, f1.y, f1.z, f1.w};
        cvt8(v, qh[kt], ql[kt]);
    }

    f32x4v o[8] = {};
    float m_run[4], l_run[4];
    #pragma unroll
    for (int r = 0; r < 4; r++) { m_run[r] = -1e30f; l_run[r] = 0.f; }

    for (int j0 = s * SPAN; j0 < (s + 1) * SPAN; j0 += 64) {
        __syncthreads();   // A: previous iteration's P/V LDS reads complete
        // ---- stage K (bf16 direct copies, swizzled)
        #pragma unroll
        for (int g = 0; g < 4; g++) {
            const int cid = g * 256 + tid;
            const int n = cid >> 4, k8 = cid & 15;
            const long gsrc = (long)(j0 + n) * D + h * 128 + k8 * 8;
            const int off = n * 128 + ((k8 ^ (n & 15)) << 3);
            *(bf16x8*)&Kh[off] = *(const bf16x8*)&Khi[gsrc];
            *(bf16x8*)&Kl[off] = *(const bf16x8*)&Klo[gsrc];
        }
        // ---- stage V
        #pragma unroll
        for (int g = 0; g < 4; g++) {
            const int cid = g * 256 + tid;
            const int d = cid >> 3, k8 = cid & 7;
            const long gsrc = (long)(h * 128 + d) * N + j0 + k8 * 8;
            const int off = d * 64 + ((k8 ^ (d & 7)) << 3);
            *(bf16x8*)&Vh[off] = *(const bf16x8*)&Vthi[gsrc];
            *(bf16x8*)&Vl[off] = *(const bf16x8*)&Vtlo[gsrc];
        }
        __syncthreads();   // B: staging visible

        // ---- S = Q K^T : this wave computes its 16 rows x 64 cols
        f32x4v sacc[4] = {};
        #pragma unroll
        for (int jb = 0; jb < 4; jb++) {
            bf16x8 kh[4], km[4];
            #pragma unroll
            for (int kt = 0; kt < 4; kt++) {
                const int col = jb * 16 + fr;
                const int k8 = kt * 4 + fq;
                const int off = col * 128 + ((k8 ^ (col & 15)) << 3);
                kh[kt] = *(const bf16x8*)&Kh[off];
                km[kt] = *(const bf16x8*)&Kl[off];
            }
            #pragma unroll
            for (int kt = 0; kt < 4; kt++) {
                sacc[jb] = __builtin_amdgcn_mfma_f32_16x16x32_bf16(ql[kt], kh[kt], sacc[jb], 0, 0, 0);
                sacc[jb] = __builtin_amdgcn_mfma_f32_16x16x32_bf16(qh[kt], km[kt], sacc[jb], 0, 0, 0);
                sacc[jb] = __builtin_amdgcn_mfma_f32_16x16x32_bf16(qh[kt], kh[kt], sacc[jb], 0, 0, 0);
            }
        }

        // ---- online softmax (log2 domain), fully within-wave
        float t[4][4], mloc[4];
        #pragma unroll
        for (int r = 0; r < 4; r++) {
            float a = sacc[0][r] * TS, b = sacc[1][r] * TS;
            float c = sacc[2][r] * TS, d2 = sacc[3][r] * TS;
            t[0][r] = a; t[1][r] = b; t[2][r] = c; t[3][r] = d2;
            mloc[r] = fmaxf(fmaxf(a, b), fmaxf(c, d2));
        }
        #pragma unroll
        for (int bmask = 1; bmask <= 8; bmask <<= 1)
            #pragma unroll
            for (int r = 0; r < 4; r++)
                mloc[r] = fmaxf(mloc[r], __shfl_xor(mloc[r], bmask));
        float alpha_[4], rs[4];
        #pragma unroll
        for (int r = 0; r < 4; r++) {
            const float mn = fmaxf(m_run[r], mloc[r]);
            alpha_[r] = exp2f(m_run[r] - mn);
            m_run[r] = mn;
            rs[r] = 0.f;
        }
        __syncthreads();   // C: all waves' K-fragment reads complete (P overlays K)
        #pragma unroll
        for (int jb = 0; jb < 4; jb++)
            #pragma unroll
            for (int r = 0; r < 4; r++) {
                const float p = exp2f(t[jb][r] - m_run[r]);
                rs[r] += p;
                const bf16 ph_ = (bf16)p;
                const int pidx = (fq * 4 + r) * PSTR + jb * 16 + fr;
                Phi[pidx] = ph_;
                Plo[pidx] = (bf16)(p - (float)ph_);
            }
        #pragma unroll
        for (int bmask = 1; bmask <= 8; bmask <<= 1)
            #pragma unroll
            for (int r = 0; r < 4; r++)
                rs[r] += __shfl_xor(rs[r], bmask);
        #pragma unroll
        for (int r = 0; r < 4; r++)
            l_run[r] = l_run[r] * alpha_[r] + rs[r];
        #pragma unroll
        for (int jbo = 0; jbo < 8; jbo++)
            #pragma unroll
            for (int r = 0; r < 4; r++)
                o[jbo][r] *= alpha_[r];

        // ---- PV: O[16 x 128] += P[16 x 64] V[64 x 128]  (P wave-private, no barrier)
        bf16x8 ph[2], pl[2];
        #pragma unroll
        for (int kt = 0; kt < 2; kt++) {
            const int pidx = fr * PSTR + kt * 32 + fq * 8;
            ph[kt] = *(const bf16x8*)&Phi[pidx];
            pl[kt] = *(const bf16x8*)&Plo[pidx];
        }
        #pragma unroll
        for (int jbo = 0; jbo < 8; jbo++) {
            bf16x8 vh_[2], vl_[2];
            #pragma unroll
            for (int kt = 0; kt < 2; kt++) {
                const int col = jbo * 16 + fr;
                const int k8 = kt * 4 + fq;
                const int off = col * 64 + ((k8 ^ (col & 7)) << 3);
                vh_[kt] = *(const bf16x8*)&Vh[off];
                vl_[kt] = *(const bf16x8*)&Vl[off];
            }
            #pragma unroll
            for (int kt = 0; kt < 2; kt++) {
                o[jbo] = __builtin_amdgcn_mfma_f32_16x16x32_bf16(pl[kt], vh_[kt], o[jbo], 0, 0, 0);
                o[jbo] = __builtin_amdgcn_mfma_f32_16x16x32_bf16(ph[kt], vl_[kt], o[jbo], 0, 0, 0);
                o[jbo] = __builtin_amdgcn_mfma_f32_16x16x32_bf16(ph[kt], vh_[kt], o[jbo], 0, 0, 0);
            }
        }
    }

    // ---- store unnormalized partial O + (m, l)
    const long sidx = ((long)(h * 64 + qt)) * 2 + s;
    float* ob = Op + sidx * 8192;
    #pragma unroll
    for (int jbo = 0; jbo < 8; jbo++)
        #pragma unroll
        for (int r = 0; r < 4; r++) {
            const int lrow = wave * 16 + fq * 4 + r;
            ob[lrow * 128 + jbo * 16 + fr] = o[jbo][r];
        }
    if (fr == 0) {
        #pragma unroll
        for (int r = 0; r < 4; r++) {
            const int lrow = wave * 16 + fq * 4 + r;
            ml[sidx * 128 + lrow]      = m_run[r];
            ml[sidx * 128 + 64 + lrow] = l_run[r];
        }
    }
}

// ---------------------------------------------------------------- merge 2 KV-splits (exact)
__global__ void flash_merge(const float* __restrict__ Op, const float* __restrict__ ml,
                            float* __restrict__ ctx)
{
    const int idx = blockIdx.x;            // h*64 + qt
    const int h = idx >> 6, qt = idx & 63;
    const int tid = threadIdx.x;
    const long b0 = ((long)idx * 2) * 8192, b1 = b0 + 8192;
    __shared__ float e0s[64], e1s[64], il[64];
    if (tid < 64) {
        const float m0 = ml[(long)(idx * 2) * 128 + tid];
        const float l0 = ml[(long)(idx * 2) * 128 + 64 + tid];
        const float m1 = ml[(long)(idx * 2 + 1) * 128 + tid];
        const float l1 = ml[(long)(idx * 2 + 1) * 128 + 64 + tid];
        const float mx = fmaxf(m0, m1);
        const float e0 = exp2f(m0 - mx), e1 = exp2f(m1 - mx);
        e0s[tid] = e0; e1s[tid] = e1;
        il[tid] = 1.f / (e0 * l0 + e1 * l1);
    }
    __syncthreads();
    #pragma unroll
    for (int i = 0; i < 32; i++) {
        const int e = tid + i * 256;
        const int row = e >> 7, col = e & 127;
        const float v = (e0s[row] * Op[b0 + e] + e1s[row] * Op[b1 + e]) * il[row];
        ctx[(long)(qt * 64 + row) * 512 + h * 128 + col] = v;
    }
}

// ---------------------------------------------------------------- residual + layernorm (f32, D=512)
__global__ void add_ln_f32(const float* __restrict__ a, const float* __restrict__ b,
                           const float* __restrict__ g, const float* __restrict__ be,
                           float* __restrict__ out)
{
    const long row = blockIdx.x;
    const int tid = threadIdx.x;
    const long base = row * 512L;
    float x0 = a[base + tid]       + b[base + tid];
    float x1 = a[base + tid + 256] + b[base + tid + 256];
    float s = block_reduce_sum256(x0 + x1);
    float mu = s * (1.f / 512.f);
    float d0 = x0 - mu, d1 = x1 - mu;
    float var = block_reduce_sum256(d0 * d0 + d1 * d1) * (1.f / 512.f);
    float invs = rsqrtf(var + 1e-6f);
    out[base + tid]       = d0 * invs * g[tid]       + be[tid];
    out[base + tid + 256] = d1 * invs * g[tid + 256] + be[tid + 256];
}

// ---------------------------------------------------------------- normalize emb rows (f32, E=512)
__global__ void normalize_emb(const float* __restrict__ emb, float* __restrict__ embn)
{
    const long row = blockIdx.x;
    const int tid = threadIdx.x;
    const long base = row * 512L;
    float a0 = emb[base + tid];
    float a1 = emb[base + tid + 256];
    float ss = block_reduce_sum256(a0 * a0 + a1 * a1);
    float sc = rsqrtf(fmaxf(ss, 1e-12f));
    embn[base + tid]       = a0 * sc;
    embn[base + tid + 256] = a1 * sc;
}

// ---------------------------------------------------------------- VQ: argmax -> one-hot in place + gather vq_feat
__global__ void vq_select_onehot(float* __restrict__ sims, const float* __restrict__ emb,
                                 float* __restrict__ vq_out)
{
    __shared__ float sv[256];
    __shared__ int   si[256];
    const long row = blockIdx.x;
    const int tid = threadIdx.x;
    float* s = sims + row * 1024L;
    float v0 = s[tid], v1 = s[tid + 256], v2 = s[tid + 512], v3 = s[tid + 768];
    float best = v0; int bi = tid;
    if (v1 > best) { best = v1; bi = tid + 256; }
    if (v2 > best) { best = v2; bi = tid + 512; }
    if (v3 > best) { best = v3; bi = tid + 768; }
    sv[tid] = best; si[tid] = bi; __syncthreads();
    #pragma unroll
    for (int st = 128; st > 0; st >>= 1) {
        if (tid < st) {
            if (sv[tid + st] > sv[tid] ||
                (sv[tid + st] == sv[tid] && si[tid + st] < si[tid])) {
                sv[tid] = sv[tid + st]; si[tid] = si[tid + st];
            }
        }
        __syncthreads();
    }
    const int idx = si[0];
    s[tid]       = (tid       == idx) ? 1.f : 0.f;
    s[tid + 256] = (tid + 256 == idx) ? 1.f : 0.f;
    s[tid + 512] = (tid + 512 == idx) ? 1.f : 0.f;
    s[tid + 768] = (tid + 768 == idx) ? 1.f : 0.f;
    const float* er = emb + (long)idx * 512;
    float* vr = vq_out + row * 512L;
    vr[tid]       = er[tid];
    vr[tid + 256] = er[tid + 256];
}

// ---------------------------------------------------------------- host side
struct EncW {
    const float *wq, *wk, *wv, *wo, *w1, *w2;      // natural [K][N]
    const float *bq, *bk, *bv, *bo, *b1, *b2;
    const float *g1, *be1, *g2, *be2;
};

static void run_encoder_g3(hipStream_t stream, const float* x, const EncW& w,
                           float* qb, bf16* khi, bf16* klo, bf16* vthi, bf16* vtlo,
                           float* ctx, float* Op, float* ml,
                           float* x1, float* hb, float* out)
{
    const int N = 4096, D = 512;
    // projections: BM=64 tiles -> 256 blocks each
    gemm3<64, false, false, true, false><<<dim3(4, 64), 256, 0, stream>>>(
        x, w.wq, w.bq, qb, nullptr, nullptr, D, D, D, D, 1.f);
    gemm3<64, false, false, true, true><<<dim3(4, 64), 256, 0, stream>>>(
        x, w.wk, w.bk, nullptr, khi, klo, D, D, D, D, 1.f);
    gemm3<64, false, true, true, true><<<dim3(4, 64), 256, 0, stream>>>(
        x, w.wv, w.bv, nullptr, vthi, vtlo, D, D, D, N, 1.f);
    // fused attention: 512 blocks (2 KV-splits), then exact merge -> ctx
    flash_attn<<<dim3(64, 4, 2), 256, 0, stream>>>(qb, khi, klo, vthi, vtlo, Op, ml);
    flash_merge<<<256, 256, 0, stream>>>(Op, ml, ctx);
    // wo projection, LN1, FFN, LN2
    gemm3<64, false, false, true, false><<<dim3(4, 64), 256, 0, stream>>>(
        ctx, w.wo, w.bo, qb, nullptr, nullptr, D, D, D, D, 1.f);
    add_ln_f32<<<N, 256, 0, stream>>>(x, qb, w.g1, w.be1, x1);
    gemm3<64, true, false, true, false><<<dim3(4, 64), 256, 0, stream>>>(
        x1, w.w1, w.b1, hb, nullptr, nullptr, D, D, D, D, 1.f);
    gemm3<64, false, false, true, false><<<dim3(4, 64), 256, 0, stream>>>(
        hb, w.w2, w.b2, qb, nullptr, nullptr, D, D, D, D, 1.f);
    add_ln_f32<<<N, 256, 0, stream>>>(x1, qb, w.g2, w.be2, out);
}

extern "C" void kernel_launch(void* const* d_in, const int* in_sizes, int n_in,
                              void* d_out, int out_size, void* d_ws, size_t ws_size,
                              hipStream_t stream)
{
    const int N = 4096, D = 512, E = 512, F = 4096, KCB = 1024;
    (void)in_sizes; (void)n_in; (void)out_size; (void)d_ws; (void)ws_size;

    const float* x_in  = (const float*)d_in[0];
    const float* fc1_w = (const float*)d_in[33];
    const float* fc1_b = (const float*)d_in[34];
    const float* fc2_w = (const float*)d_in[35];
    const float* fc2_b = (const float*)d_in[36];
    const float* emb   = (const float*)d_in[37];

    // ---- output regions (f32); context_ind = one-hot [N, K]
    float* out0 = (float*)d_out;                  // encoded [N,E]       8 MB
    float* out1 = out0 + (size_t)N * E;           // vq_feat [N,E]       8 MB
    float* out2 = out1 + (size_t)N * E;           // one_hot [N,K]      16 MB
    float* out3 = out2 + (size_t)N * KCB;         // decoded [N,F]      64 MB
    float* out4 = out3 + (size_t)N * F;           // emb copy [K,E]      2 MB

    // ---- arena inside out3 (64 MB); dead before the fc2 writes reach it
    char* arena = (char*)out3;
    const size_t MB = 1024 * 1024;
    float* qb     = (float*)(arena + 0 * MB);     // [0,8)
    bf16*  khi    = (bf16*) (arena + 8 * MB);     // [8,12)
    bf16*  klo    = (bf16*) (arena + 12 * MB);    // [12,16)
    bf16*  vthi   = (bf16*) (arena + 16 * MB);    // [16,20)
    bf16*  vtlo   = (bf16*) (arena + 20 * MB);    // [20,24)
    float* ctx    = (float*)(arena + 24 * MB);    // [24,32)
    float* Op     = (float*)(arena + 32 * MB);    // [32,48): 512 x 64 x 128 f32 partials
    float* ml     = (float*)(arena + 48 * MB);    // [48,48.25)
    float* decout = (float*)(arena + 56 * MB);    // [56,64)
    float* x1     = (float*)(arena + 16 * MB);    // reuse KV region after attention
    float* hb     = (float*)(arena + 8 * MB);
    float* embn   = out1;                         // dead until vq_select
    float* stage  = (float*)out4;                 // staging (emb copied last)

    EncW ew = { (const float*)d_in[1],  (const float*)d_in[2],  (const float*)d_in[3],
                (const float*)d_in[4],  (const float*)d_in[5],  (const float*)d_in[6],
                (const float*)d_in[7],  (const float*)d_in[8],  (const float*)d_in[9],
                (const float*)d_in[10], (const float*)d_in[11], (const float*)d_in[12],
                (const float*)d_in[13], (const float*)d_in[14], (const float*)d_in[15],
                (const float*)d_in[16] };
    EncW dw = { (const float*)d_in[17], (const float*)d_in[18], (const float*)d_in[19],
                (const float*)d_in[20], (const float*)d_in[21], (const float*)d_in[22],
                (const float*)d_in[23], (const float*)d_in[24], (const float*)d_in[25],
                (const float*)d_in[26], (const float*)d_in[27], (const float*)d_in[28],
                (const float*)d_in[29], (const float*)d_in[30], (const float*)d_in[31],
                (const float*)d_in[32] };

    // ---- phase E: encoder -> ctx
    normalize_emb<<<KCB, 256, 0, stream>>>(emb, embn);
    run_encoder_g3(stream, x_in, ew, qb, khi, klo, vthi, vtlo, ctx, Op, ml, x1, hb, ctx);

    // ---- phase F: fc1 -> encoded (out0)
    gemm3<64, false, false, true, false><<<dim3(4, 64), 256, 0, stream>>>(
        ctx, fc1_w, fc1_b, out0, nullptr, nullptr, D, D, E, E, 1.f);

    // ---- phase V: sims = encoded @ embn^T into out2; argmax -> one-hot + gather
    gemm3<128, false, false, false, false><<<dim3(8, 32), 256, 0, stream>>>(
        out0, embn, nullptr, out2, nullptr, nullptr, E, E, E, KCB, 1.f);
    vq_select_onehot<<<N, 256, 0, stream>>>(out2, emb, out1);

    // ---- phase D: decoder -> decout [56,64)
    run_encoder_g3(stream, out1, dw, qb, khi, klo, vthi, vtlo, ctx, Op, ml, x1, hb, decout);

    // ---- phase G: fc2 + relu (B natural). Rows [0,3584) write [0,56M) (disjoint
    // from decout); rows [3584,4096) read a staged copy since their writes cover decout.
    hipMemcpyAsync(stage, decout + (size_t)3584 * D, (size_t)512 * D * sizeof(float),
                   hipMemcpyDeviceToDevice, stream);
    gemm3<128, true, false, true, false><<<dim3(F / 128, 3584 / 128), 256, 0, stream>>>(
        decout, fc2_w, fc2_b, out3, nullptr, nullptr, D, D, F, F, 1.f);
    gemm3<128, true, false, true, false><<<dim3(F / 128, 512 / 128), 256, 0, stream>>>(
        stage, fc2_w, fc2_b, out3 + (size_t)3584 * F, nullptr, nullptr, D, D, F, F, 1.f);

    // ---- emb copy last (out4 was staging)
    hipMemcpyAsync(out4, emb, (size_t)KCB * E * sizeof(float), hipMemcpyDeviceToDevice, stream);
}